// Round 1
// baseline (4736.566 us; speedup 1.0000x reference)
//
#include <hip/hip_runtime.h>
#include <math.h>

#define HH 512
#define NHEADS 4
#define HD 128
#define HALF 64
#define FFND 2048
#define BB 4
#define SS 2048
#define NLAYERS 3
#define ROWS (BB*SS)   // 8192
#define EPSF 1e-5f

// ---------------------------------------------------------------- xpos tables
__global__ void k_tables(float* __restrict__ cq, float* __restrict__ sq,
                         float* __restrict__ ck, float* __restrict__ sk) {
    int i = threadIdx.x;          // 0..63 (half-dim)
    int s = blockIdx.x;           // 0..2047 (position)
    float si   = ((float)i + 0.4f * (float)HD) / (1.4f * (float)HD);
    float scale = powf(si, (float)s / 512.0f);
    float invf = powf(10000.0f, -((float)i) / (float)HALF);
    float ang  = (float)s * invf;
    float c = cosf(ang), sn = sinf(ang);
    int idx = s * HALF + i;
    cq[idx] = c * scale;   sq[idx] = sn * scale;
    float is = 1.0f / scale;
    ck[idx] = c * is;      sk[idx] = sn * is;
}

// ---------------------------------------------------------------- layernorm (wave per row)
__global__ __launch_bounds__(256) void k_layernorm(
    const float* __restrict__ x, const float* __restrict__ w,
    const float* __restrict__ b, float* __restrict__ y) {
    int lane = threadIdx.x & 63;
    int row  = blockIdx.x * 4 + (threadIdx.x >> 6);
    const float4* xr = (const float4*)(x + (size_t)row * HH);
    float4 v0 = xr[lane * 2];
    float4 v1 = xr[lane * 2 + 1];
    float s  = v0.x + v0.y + v0.z + v0.w + v1.x + v1.y + v1.z + v1.w;
    float ss = v0.x*v0.x + v0.y*v0.y + v0.z*v0.z + v0.w*v0.w
             + v1.x*v1.x + v1.y*v1.y + v1.z*v1.z + v1.w*v1.w;
    for (int off = 32; off > 0; off >>= 1) {
        s  += __shfl_xor(s, off);
        ss += __shfl_xor(ss, off);
    }
    float m   = s * (1.0f / HH);
    float var = ss * (1.0f / HH) - m * m;
    float inv = rsqrtf(var + EPSF);
    int h0 = lane * 8;
    float4 wa = *(const float4*)(w + h0);
    float4 wb = *(const float4*)(w + h0 + 4);
    float4 ba = *(const float4*)(b + h0);
    float4 bb2 = *(const float4*)(b + h0 + 4);
    float4 o0, o1;
    o0.x = (v0.x - m) * inv * wa.x + ba.x;
    o0.y = (v0.y - m) * inv * wa.y + ba.y;
    o0.z = (v0.z - m) * inv * wa.z + ba.z;
    o0.w = (v0.w - m) * inv * wa.w + ba.w;
    o1.x = (v1.x - m) * inv * wb.x + bb2.x;
    o1.y = (v1.y - m) * inv * wb.y + bb2.y;
    o1.z = (v1.z - m) * inv * wb.z + bb2.z;
    o1.w = (v1.w - m) * inv * wb.w + bb2.w;
    float4* y4 = (float4*)(y + (size_t)row * HH + h0);
    y4[0] = o0; y4[1] = o1;
}

// ---------------------------------------------------------------- xpos rotate Q,K in place
__global__ __launch_bounds__(256) void k_xpos(
    float* __restrict__ Q, float* __restrict__ Kp,
    const float* __restrict__ cq, const float* __restrict__ sq,
    const float* __restrict__ ck, const float* __restrict__ sk) {
    int row = blockIdx.x;                 // b*S + s
    int p   = threadIdx.x;                // pair index within row, 0..255
    int s   = row & (SS - 1);
    int i   = p & (HALF - 1);             // half-dim index within head
    int ti  = s * HALF + i;
    size_t base = (size_t)row * HH + p * 2;
    float2 q = *(float2*)(Q + base);
    float c = cq[ti], sn = sq[ti];
    float2 qo; qo.x = q.x * c - q.y * sn; qo.y = q.y * c + q.x * sn;
    *(float2*)(Q + base) = qo;
    float2 k = *(float2*)(Kp + base);
    c = ck[ti]; sn = sk[ti];
    float2 ko; ko.x = k.x * c - k.y * sn; ko.y = k.y * c + k.x * sn;
    *(float2*)(Kp + base) = ko;
}

// ---------------------------------------------------------------- retention (flash-style, triangular)
__global__ __launch_bounds__(256) void k_retention(
    const float* __restrict__ Q, const float* __restrict__ K,
    const float* __restrict__ V, float* __restrict__ Y) {
    __shared__ float Qs[64][132];
    __shared__ float Ks[32][132];
    __shared__ float Vs[32][132];
    __shared__ float As[64][36];
    int tid = threadIdx.x;
    int s0 = blockIdx.x * 64;
    int n  = blockIdx.y, b = blockIdx.z;
    // per-head gamma, replicating np: 1 - exp(linspace(log(1/32), log(1/512), 4))
    double la = log(1.0 / 32.0), lb = log(1.0 / 512.0);
    float gamma = (float)(1.0 - exp(la + (lb - la) * (double)n / 3.0));
    float l2g = log2f(gamma);
    size_t base = ((size_t)b * SS) * HH + (size_t)n * HD;
    // stage Q tile (64 x 128)
    for (int idx = tid; idx < 64 * 32; idx += 256) {
        int r = idx >> 5, c = idx & 31;
        ((float4*)Qs[r])[c] = ((const float4*)(Q + base + (size_t)(s0 + r) * HH))[c];
    }
    float acc[4][8];
    #pragma unroll
    for (int i = 0; i < 4; ++i)
        #pragma unroll
        for (int j = 0; j < 8; ++j) acc[i][j] = 0.0f;
    int rg = tid >> 4, cg = tid & 15;
    int ntile = (s0 >> 5) + 2;
    for (int t = 0; t < ntile; ++t) {
        int t0 = t * 32;
        for (int idx = tid; idx < 32 * 32; idx += 256) {
            int r = idx >> 5, c = idx & 31;
            ((float4*)Ks[r])[c] = ((const float4*)(K + base + (size_t)(t0 + r) * HH))[c];
            ((float4*)Vs[r])[c] = ((const float4*)(V + base + (size_t)(t0 + r) * HH))[c];
        }
        __syncthreads();
        // phase 1: A[64][32] = Q . K^T  (each thread: 4 rows x 2 cols)
        float pa[4][2] = {{0.0f, 0.0f}, {0.0f, 0.0f}, {0.0f, 0.0f}, {0.0f, 0.0f}};
        #pragma unroll 4
        for (int k4 = 0; k4 < 32; ++k4) {
            float4 ka = ((const float4*)Ks[cg * 2])[k4];
            float4 kb = ((const float4*)Ks[cg * 2 + 1])[k4];
            #pragma unroll
            for (int i = 0; i < 4; ++i) {
                float4 q = ((const float4*)Qs[rg * 4 + i])[k4];
                pa[i][0] += q.x * ka.x + q.y * ka.y + q.z * ka.z + q.w * ka.w;
                pa[i][1] += q.x * kb.x + q.y * kb.y + q.z * kb.z + q.w * kb.w;
            }
        }
        #pragma unroll
        for (int i = 0; i < 4; ++i)
            #pragma unroll
            for (int j = 0; j < 2; ++j) {
                int sr = s0 + rg * 4 + i, tc = t0 + cg * 2 + j;
                float d = (sr >= tc) ? exp2f(l2g * (float)(sr - tc)) : 0.0f;
                As[rg * 4 + i][cg * 2 + j] = pa[i][j] * d;
            }
        __syncthreads();
        // phase 2: Y[64][128] += A . V  (each thread: 4 rows x 8 cols)
        #pragma unroll 4
        for (int k = 0; k < 32; ++k) {
            float4 va = ((const float4*)Vs[k])[cg * 2];
            float4 vb = ((const float4*)Vs[k])[cg * 2 + 1];
            #pragma unroll
            for (int i = 0; i < 4; ++i) {
                float a = As[rg * 4 + i][k];
                acc[i][0] += a * va.x; acc[i][1] += a * va.y;
                acc[i][2] += a * va.z; acc[i][3] += a * va.w;
                acc[i][4] += a * vb.x; acc[i][5] += a * vb.y;
                acc[i][6] += a * vb.z; acc[i][7] += a * vb.w;
            }
        }
        __syncthreads();
    }
    #pragma unroll
    for (int i = 0; i < 4; ++i) {
        float4 oa = {acc[i][0], acc[i][1], acc[i][2], acc[i][3]};
        float4 ob = {acc[i][4], acc[i][5], acc[i][6], acc[i][7]};
        float* yp = Y + base + (size_t)(s0 + rg * 4 + i) * HH + cg * 8;
        ((float4*)yp)[0] = oa;
        ((float4*)yp)[1] = ob;
    }
}

// ---------------------------------------------------------------- groupnorm + silu gate
__global__ __launch_bounds__(256) void k_gate(
    const float* __restrict__ Yr, const float* __restrict__ G,
    const float* __restrict__ gw, const float* __restrict__ gb,
    float* __restrict__ E) {
    int lane = threadIdx.x & 63;
    int grp  = blockIdx.x * 4 + (threadIdx.x >> 6);   // (b*S + s)*4 + n
    int row = grp >> 2, n = grp & 3;
    size_t off = (size_t)row * HH + n * HD + lane * 2;
    float2 v = *(const float2*)(Yr + off);
    float s = v.x + v.y, ss = v.x * v.x + v.y * v.y;
    for (int o = 32; o > 0; o >>= 1) {
        s  += __shfl_xor(s, o);
        ss += __shfl_xor(ss, o);
    }
    float m   = s * (1.0f / HD);
    float var = ss * (1.0f / HD) - m * m;
    float inv = rsqrtf(var + EPSF);
    int h = n * HD + lane * 2;
    float2 g  = *(const float2*)(G + off);
    float2 w  = *(const float2*)(gw + h);
    float2 bv = *(const float2*)(gb + h);
    float yn0 = (v.x - m) * inv * w.x + bv.x;
    float yn1 = (v.y - m) * inv * w.y + bv.y;
    float e0 = g.x / (1.0f + expf(-g.x)) * yn0;
    float e1 = g.y / (1.0f + expf(-g.y)) * yn1;
    float2 eo = {e0, e1};
    *(float2*)(E + off) = eo;
}

// ---------------------------------------------------------------- generic tiled fp32 GEMM
// BMODE 0: B[k][col] = Bp[(col>>7)*sH + k*sK + (col&127)]  (covers per-head & row-major)
// BMODE 1: B[k][col] = Bp[col*sK + k]                       (transposed, for Gram)
// EPI: 0 none | 1 +bias, gelu | 2 +bias +resid | 3 +resid
__device__ inline float gelu_f(float x) {
    return 0.5f * x * (1.0f + erff(x * 0.70710678118654752f));
}

template<int BMODE, int EPI>
__global__ __launch_bounds__(256) void k_gemm(
    const float* __restrict__ A, const float* __restrict__ Bp,
    float* __restrict__ C, const float* __restrict__ bias,
    const float* __restrict__ Rs,
    int M, int N, int K, int sH, int sK,
    size_t aBat, size_t bBat, size_t cBat) {
    __shared__ float As[16][68];
    __shared__ float Bs[16][68];
    int bz = blockIdx.z;
    A  += (size_t)bz * aBat;
    Bp += (size_t)bz * bBat;
    C  += (size_t)bz * cBat;
    if (EPI >= 2) Rs += (size_t)bz * cBat;
    int m0 = blockIdx.x * 64, n0 = blockIdx.y * 64;
    int tid = threadIdx.x;
    int tx = tid & 15, ty = tid >> 4;
    float acc[4][4];
    #pragma unroll
    for (int i = 0; i < 4; ++i)
        #pragma unroll
        for (int j = 0; j < 4; ++j) acc[i][j] = 0.0f;
    for (int k0 = 0; k0 < K; k0 += 16) {
        #pragma unroll
        for (int it = 0; it < 4; ++it) {
            int idx = tid + it * 256;
            int m = idx >> 4, kk = idx & 15;
            As[kk][m] = A[(size_t)(m0 + m) * K + k0 + kk];
        }
        if (BMODE == 0) {
            #pragma unroll
            for (int it = 0; it < 4; ++it) {
                int idx = tid + it * 256;
                int kk = idx >> 6, j = idx & 63;
                int col = n0 + j;
                Bs[kk][j] = Bp[(size_t)(col >> 7) * sH + (size_t)(k0 + kk) * sK + (col & 127)];
            }
        } else {
            #pragma unroll
            for (int it = 0; it < 4; ++it) {
                int idx = tid + it * 256;
                int j = idx >> 4, kk = idx & 15;
                Bs[kk][j] = Bp[(size_t)(n0 + j) * sK + k0 + kk];
            }
        }
        __syncthreads();
        #pragma unroll
        for (int kk = 0; kk < 16; ++kk) {
            float4 av = *(const float4*)&As[kk][ty * 4];
            float4 bv = *(const float4*)&Bs[kk][tx * 4];
            float a[4] = {av.x, av.y, av.z, av.w};
            float bq[4] = {bv.x, bv.y, bv.z, bv.w};
            #pragma unroll
            for (int i = 0; i < 4; ++i)
                #pragma unroll
                for (int j = 0; j < 4; ++j)
                    acc[i][j] += a[i] * bq[j];
        }
        __syncthreads();
    }
    #pragma unroll
    for (int i = 0; i < 4; ++i) {
        size_t row = m0 + ty * 4 + i;
        size_t c0 = n0 + tx * 4;
        float4 v = {acc[i][0], acc[i][1], acc[i][2], acc[i][3]};
        if (EPI == 1) {
            float4 b4 = *(const float4*)(bias + c0);
            v.x = gelu_f(v.x + b4.x); v.y = gelu_f(v.y + b4.y);
            v.z = gelu_f(v.z + b4.z); v.w = gelu_f(v.w + b4.w);
        } else if (EPI == 2) {
            float4 b4 = *(const float4*)(bias + c0);
            float4 r4 = *(const float4*)(Rs + row * N + c0);
            v.x += b4.x + r4.x; v.y += b4.y + r4.y;
            v.z += b4.z + r4.z; v.w += b4.w + r4.w;
        } else if (EPI == 3) {
            float4 r4 = *(const float4*)(Rs + row * N + c0);
            v.x += r4.x; v.y += r4.y; v.z += r4.z; v.w += r4.w;
        }
        *(float4*)(C + row * N + c0) = v;
    }
}

// ---------------------------------------------------------------- launch
extern "C" void kernel_launch(void* const* d_in, const int* in_sizes, int n_in,
                              void* d_out, int out_size, void* d_ws, size_t ws_size,
                              hipStream_t stream) {
    const float* X0  = (const float*)d_in[0];
    const float* WQ  = (const float*)d_in[1];
    const float* WK  = (const float*)d_in[2];
    const float* WV  = (const float*)d_in[3];
    const float* WG  = (const float*)d_in[4];
    const float* WO  = (const float*)d_in[5];
    const float* gnw = (const float*)d_in[6];
    const float* gnb = (const float*)d_in[7];
    const float* l1w = (const float*)d_in[8];
    const float* l1b = (const float*)d_in[9];
    const float* l2w = (const float*)d_in[10];
    const float* l2b = (const float*)d_in[11];
    const float* fw1 = (const float*)d_in[12];
    const float* fb1 = (const float*)d_in[13];
    const float* fw2 = (const float*)d_in[14];
    const float* fb2 = (const float*)d_in[15];
    float* outX = (float*)d_out;
    float* outG = outX + (size_t)BB * SS * HH;
    float* ws = (float*)d_ws;
    const size_t R = (size_t)ROWS * HH;     // 4,194,304
    float* cq = ws;
    float* sq = cq + (size_t)SS * HALF;
    float* ck = sq + (size_t)SS * HALF;
    float* sk = ck + (size_t)SS * HALF;
    float* t0p = sk + (size_t)SS * HALF;
    float* bufXn = t0p;
    float* bufQ  = t0p + R;
    float* bufK  = t0p + 2 * R;
    float* bufV  = t0p + 3 * R;
    float* bufYr = t0p + 4 * R;
    float* bufX  = t0p + 5 * R;
    float* bufH  = t0p + 6 * R;             // 4R (8192 x 2048)
    float* bufG = bufK;                     // K dead after retention
    float* bufE = bufQ;                     // Q dead after retention
    float* bufY = bufV;                     // V dead after retention

    k_tables<<<SS, HALF, 0, stream>>>(cq, sq, ck, sk);

    const float* curX = X0;
    for (int l = 0; l < NLAYERS; ++l) {
        k_layernorm<<<ROWS / 4, 256, 0, stream>>>(curX, l1w + l * HH, l1b + l * HH, bufXn);
        dim3 g1(ROWS / 64, HH / 64, 1);
        size_t wqoff = (size_t)l * NHEADS * HH * HD;
        k_gemm<0, 0><<<g1, 256, 0, stream>>>(bufXn, WQ + wqoff, bufQ, nullptr, nullptr,
                                             ROWS, HH, HH, HH * HD, HD, 0, 0, 0);
        k_gemm<0, 0><<<g1, 256, 0, stream>>>(bufXn, WK + wqoff, bufK, nullptr, nullptr,
                                             ROWS, HH, HH, HH * HD, HD, 0, 0, 0);
        k_gemm<0, 0><<<g1, 256, 0, stream>>>(bufXn, WV + wqoff, bufV, nullptr, nullptr,
                                             ROWS, HH, HH, HH * HD, HD, 0, 0, 0);
        k_xpos<<<ROWS, 256, 0, stream>>>(bufQ, bufK, cq, sq, ck, sk);
        k_retention<<<dim3(SS / 64, NHEADS, BB), 256, 0, stream>>>(bufQ, bufK, bufV, bufYr);
        k_gemm<0, 0><<<g1, 256, 0, stream>>>(bufXn, WG + (size_t)l * HH * HH, bufG,
                                             nullptr, nullptr, ROWS, HH, HH, HD, HH, 0, 0, 0);
        k_gate<<<ROWS, 256, 0, stream>>>(bufYr, bufG, gnw + l * HH, gnb + l * HH, bufE);
        k_gemm<0, 3><<<g1, 256, 0, stream>>>(bufE, WO + (size_t)l * HH * HH, bufY,
                                             nullptr, curX, ROWS, HH, HH, HD, HH, 0, 0, 0);
        k_layernorm<<<ROWS / 4, 256, 0, stream>>>(bufY, l2w + l * HH, l2b + l * HH, bufXn);
        dim3 g2(ROWS / 64, FFND / 64, 1);
        k_gemm<0, 1><<<g2, 256, 0, stream>>>(bufXn, fw1 + (size_t)l * HH * FFND, bufH,
                                             fb1 + l * FFND, nullptr, ROWS, FFND, HH, HD, FFND, 0, 0, 0);
        float* newX = (l == NLAYERS - 1) ? outX : bufX;
        k_gemm<0, 2><<<g1, 256, 0, stream>>>(bufH, fw2 + (size_t)l * FFND * HH, newX,
                                             fb2 + l * HH, bufY, ROWS, HH, FFND, HD, HH, 0, 0, 0);
        curX = newX;
    }
    // Gram: out1[b] = X[b] @ X[b]^T  (batched, transposed-B mode)
    dim3 g3(SS / 64, SS / 64, BB);
    k_gemm<1, 0><<<g3, 256, 0, stream>>>(outX, outX, outG, nullptr, nullptr,
                                         SS, SS, HH, 0, HH,
                                         (size_t)SS * HH, (size_t)SS * HH, (size_t)SS * SS);
}

// Round 3
// 1037.726 us; speedup vs baseline: 4.5644x; 4.5644x over previous
//
#include <hip/hip_runtime.h>
#include <math.h>

#define HH 512
#define NHEADS 4
#define HD 128
#define HALF 64
#define FFND 2048
#define BB 4
#define SS 2048
#define NLAYERS 3
#define ROWS (BB*SS)
#define EPSF 1e-5f

typedef float f32x4 __attribute__((ext_vector_type(4)));
typedef __bf16 bf16x8 __attribute__((ext_vector_type(8)));

__device__ __forceinline__ unsigned short f2bf(float f) {
    union { float f; unsigned u; } v; v.f = f;
    unsigned r = (v.u + 0x7FFFu + ((v.u >> 16) & 1u)) >> 16;
    return (unsigned short)r;
}
__device__ __forceinline__ float bf2f(unsigned short h) {
    union { unsigned u; float f; } v; v.u = ((unsigned)h) << 16;
    return v.f;
}
__device__ __forceinline__ void gl16(const void* g, void* l) {
    __builtin_amdgcn_global_load_lds((const __attribute__((address_space(1))) void*)g,
                                     (__attribute__((address_space(3))) void*)l, 16, 0, 0);
}
__device__ __forceinline__ bf16x8 ld8(const void* p) { return *(const bf16x8*)p; }

// ---------------------------------------------------------------- xpos tables (fp32, once)
__global__ void k_tables(float* __restrict__ cq, float* __restrict__ sq,
                         float* __restrict__ ck, float* __restrict__ sk) {
    int i = threadIdx.x;          // 0..63 half-dim
    int s = blockIdx.x;           // position
    float si   = ((float)i + 0.4f * (float)HD) / (1.4f * (float)HD);
    float scale = powf(si, (float)s / 512.0f);
    float invf = powf(10000.0f, -((float)i) / (float)HALF);
    float ang  = (float)s * invf;
    float c = cosf(ang), sn = sinf(ang);
    int idx = s * HALF + i;
    cq[idx] = c * scale;   sq[idx] = sn * scale;
    float is = 1.0f / scale;
    ck[idx] = c * is;      sk[idx] = sn * is;
}

// ---------------------------------------------------------------- weight transpose+cast: [K][N] fp32 -> [N][K] bf16
__global__ __launch_bounds__(256) void k_wt(const float* __restrict__ src, unsigned short* __restrict__ dst,
                                            int K, int N) {
    __shared__ float T[32][33];
    int n0 = blockIdx.x * 32, k0 = blockIdx.y * 32;
    size_t mb = (size_t)blockIdx.z * (size_t)K * N;
    src += mb; dst += mb;
    int tx = threadIdx.x & 31, ty = threadIdx.x >> 5;
    #pragma unroll
    for (int i = 0; i < 4; ++i) {
        int r = ty + i * 8;
        T[r][tx] = src[(size_t)(k0 + r) * N + n0 + tx];
    }
    __syncthreads();
    #pragma unroll
    for (int i = 0; i < 4; ++i) {
        int r = ty + i * 8;
        dst[(size_t)(n0 + r) * K + k0 + tx] = f2bf(T[tx][r]);
    }
}

// ---------------------------------------------------------------- layernorm fp32 -> bf16 (wave/row)
__global__ __launch_bounds__(256) void k_ln(const float* __restrict__ x, const float* __restrict__ w,
                                            const float* __restrict__ b, unsigned short* __restrict__ y) {
    int lane = threadIdx.x & 63;
    size_t row = (size_t)blockIdx.x * 4 + (threadIdx.x >> 6);
    const float4* xr = (const float4*)(x + row * HH);
    float4 v0 = xr[lane * 2];
    float4 v1 = xr[lane * 2 + 1];
    float s  = v0.x + v0.y + v0.z + v0.w + v1.x + v1.y + v1.z + v1.w;
    float ss = v0.x*v0.x + v0.y*v0.y + v0.z*v0.z + v0.w*v0.w
             + v1.x*v1.x + v1.y*v1.y + v1.z*v1.z + v1.w*v1.w;
    for (int off = 32; off > 0; off >>= 1) {
        s  += __shfl_xor(s, off);
        ss += __shfl_xor(ss, off);
    }
    float m   = s * (1.0f / HH);
    float var = ss * (1.0f / HH) - m * m;
    float inv = rsqrtf(var + EPSF);
    int h0 = lane * 8;
    float4 wa = *(const float4*)(w + h0);
    float4 wb = *(const float4*)(w + h0 + 4);
    float4 ba = *(const float4*)(b + h0);
    float4 bb2 = *(const float4*)(b + h0 + 4);
    unsigned short o0 = f2bf((v0.x - m) * inv * wa.x + ba.x);
    unsigned short o1 = f2bf((v0.y - m) * inv * wa.y + ba.y);
    unsigned short o2 = f2bf((v0.z - m) * inv * wa.z + ba.z);
    unsigned short o3 = f2bf((v0.w - m) * inv * wa.w + ba.w);
    unsigned short o4 = f2bf((v1.x - m) * inv * wb.x + bb2.x);
    unsigned short o5 = f2bf((v1.y - m) * inv * wb.y + bb2.y);
    unsigned short o6 = f2bf((v1.z - m) * inv * wb.z + bb2.z);
    unsigned short o7 = f2bf((v1.w - m) * inv * wb.w + bb2.w);
    uint4 pk;
    pk.x = o0 | ((unsigned)o1 << 16);
    pk.y = o2 | ((unsigned)o3 << 16);
    pk.z = o4 | ((unsigned)o5 << 16);
    pk.w = o6 | ((unsigned)o7 << 16);
    *(uint4*)(y + row * HH + h0) = pk;
}

// ---------------------------------------------------------------- xpos rotate Q,K (bf16 in place)
__global__ __launch_bounds__(256) void k_xpos(unsigned short* __restrict__ Q, unsigned short* __restrict__ Kp,
    const float* __restrict__ cq, const float* __restrict__ sq,
    const float* __restrict__ ck, const float* __restrict__ sk) {
    int row = blockIdx.x, p = threadIdx.x;
    int s = row & (SS - 1), i = p & (HALF - 1);
    int ti = s * HALF + i;
    size_t off = (size_t)row * HH + p * 2;
    unsigned qv = *(unsigned*)(Q + off);
    float x1 = bf2f(qv & 0xffff), x2 = bf2f(qv >> 16);
    float c = cq[ti], sn = sq[ti];
    unsigned short e = f2bf(x1 * c - x2 * sn), o = f2bf(x2 * c + x1 * sn);
    *(unsigned*)(Q + off) = (unsigned)e | ((unsigned)o << 16);
    unsigned kv = *(unsigned*)(Kp + off);
    x1 = bf2f(kv & 0xffff); x2 = bf2f(kv >> 16);
    c = ck[ti]; sn = sk[ti];
    e = f2bf(x1 * c - x2 * sn); o = f2bf(x2 * c + x1 * sn);
    *(unsigned*)(Kp + off) = (unsigned)e | ((unsigned)o << 16);
}

// ---------------------------------------------------------------- retention: MFMA flash-style, triangular
// LDS: Qs 0..16K (64x128 bf16, rows 256B, xor (r&7)<<4)
//      Ks 16K..32K (same)
//      VT 32K..48K (128x64 bf16, rows 128B, xor (d&7)<<4)
//      Ps 48K..56K (64x64 bf16, rows 128B, xor (r&7)<<4)
__global__ __launch_bounds__(256) void k_ret(
    const unsigned short* __restrict__ Q, const unsigned short* __restrict__ K,
    const unsigned short* __restrict__ V, float* __restrict__ Y) {
    __shared__ __align__(16) char sm[57344];
    const int tid = threadIdx.x;
    const int lane = tid & 63, wid = tid >> 6;
    const int lcol = lane & 15, lrow = lane >> 4;
    const int xs = blockIdx.x, hn = blockIdx.y, b = blockIdx.z;
    const int s0 = xs * 64;
    const double la = -3.4657359027997265, lb = -6.238324625039508;
    const float gamma = (float)(1.0 - exp(la + (lb - la) * ((double)hn / 3.0)));
    const float l2g = log2f(gamma);
    const size_t rowbase = (size_t)b * SS;
    const size_t colbase = (size_t)hn * HD;
    // stage Q tile
    #pragma unroll
    for (int c = 0; c < 4; ++c) {
        int chunk = wid * 4 + c;
        int r = chunk * 4 + lrow;
        int w = ((lane & 15) * 16) ^ ((r & 7) << 4);
        gl16((const char*)Q + ((rowbase + s0 + r) * HH + colbase) * 2 + w, sm + chunk * 1024);
    }
    float gr[4], gni[4];
    #pragma unroll
    for (int j = 0; j < 4; ++j) { gr[j] = exp2f(l2g * (float)j); gni[j] = exp2f(-l2g * (16.0f * j)); }
    f32x4 accy[8];
    #pragma unroll
    for (int i = 0; i < 8; ++i) accy[i] = f32x4{0.f, 0.f, 0.f, 0.f};
    const int nt = xs + 1;
    for (int t = 0; t < nt; ++t) {
        const int t0 = t * 64;
        __syncthreads();                       // prev readers done before restage
        #pragma unroll
        for (int c = 0; c < 4; ++c) {
            int chunk = wid * 4 + c;
            int r = chunk * 4 + lrow;
            int w = ((lane & 15) * 16) ^ ((r & 7) << 4);
            gl16((const char*)K + ((rowbase + t0 + r) * HH + colbase) * 2 + w, sm + 16384 + chunk * 1024);
        }
        {   // V^T staging (reg transpose, conflict-free b16 writes)
            const int tt = tid & 63, q4 = tid >> 6;
            #pragma unroll
            for (int j = 0; j < 4; ++j) {
                const int d0 = q4 * 32 + j * 8;
                uint4 vv = *(const uint4*)((const char*)V + ((rowbase + t0 + tt) * HH + colbase + d0) * 2);
                const unsigned short* vs = (const unsigned short*)&vv;
                #pragma unroll
                for (int e = 0; e < 8; ++e) {
                    int d = d0 + e;
                    *(unsigned short*)(sm + 32768 + d * 128 + ((tt * 2) ^ ((d & 7) << 4))) = vs[e];
                }
            }
        }
        __syncthreads();
        // QK^T (wave owns 16 rows x 64 t-cols)
        f32x4 pacc[4];
        #pragma unroll
        for (int i = 0; i < 4; ++i) pacc[i] = f32x4{0.f, 0.f, 0.f, 0.f};
        #pragma unroll
        for (int kk = 0; kk < 4; ++kk) {
            int ar = wid * 16 + lcol;
            bf16x8 af = ld8(sm + ar * 256 + ((kk * 64 + lrow * 16) ^ ((ar & 7) << 4)));
            #pragma unroll
            for (int nn = 0; nn < 4; ++nn) {
                int br = nn * 16 + lcol;
                bf16x8 bf = ld8(sm + 16384 + br * 256 + ((kk * 64 + lrow * 16) ^ ((br & 7) << 4)));
                pacc[nn] = __builtin_amdgcn_mfma_f32_16x16x32_bf16(af, bf, pacc[nn], 0, 0, 0);
            }
        }
        // decay + P -> LDS (bf16)
        const int e0 = (s0 - t0) + wid * 16 + lrow * 4 - lcol;
        const float G0 = exp2f(l2g * (float)e0);
        #pragma unroll
        for (int nn = 0; nn < 4; ++nn) {
            #pragma unroll
            for (int j = 0; j < 4; ++j) {
                const int delta = e0 + j - nn * 16;
                const float dd = (delta >= 0) ? (G0 * gr[j] * gni[nn]) : 0.0f;
                const float pv = pacc[nn][j] * dd;
                const int pr = wid * 16 + lrow * 4 + j;
                const int pc = nn * 16 + lcol;
                *(unsigned short*)(sm + 49152 + pr * 128 + ((pc * 2) ^ ((pr & 7) << 4))) = f2bf(pv);
            }
        }
        // PV (own-wave P rows -> no barrier needed)
        #pragma unroll
        for (int ks = 0; ks < 2; ++ks) {
            int ar = wid * 16 + lcol;
            bf16x8 pf = ld8(sm + 49152 + ar * 128 + ((ks * 64 + lrow * 16) ^ ((ar & 7) << 4)));
            #pragma unroll
            for (int nn = 0; nn < 8; ++nn) {
                int dr = nn * 16 + lcol;
                bf16x8 vf = ld8(sm + 32768 + dr * 128 + ((ks * 64 + lrow * 16) ^ ((dr & 7) << 4)));
                accy[nn] = __builtin_amdgcn_mfma_f32_16x16x32_bf16(pf, vf, accy[nn], 0, 0, 0);
            }
        }
    }
    #pragma unroll
    for (int nn = 0; nn < 8; ++nn)
        #pragma unroll
        for (int j = 0; j < 4; ++j) {
            size_t row = rowbase + s0 + wid * 16 + lrow * 4 + j;
            Y[row * HH + colbase + nn * 16 + lcol] = accy[nn][j];
        }
}

// ---------------------------------------------------------------- groupnorm + silu gate (Yr fp32, G bf16 -> E bf16)
__global__ __launch_bounds__(256) void k_gate(
    const float* __restrict__ Yr, const unsigned short* __restrict__ G,
    const float* __restrict__ gw, const float* __restrict__ gb,
    unsigned short* __restrict__ E) {
    int lane = threadIdx.x & 63;
    int grp  = blockIdx.x * 4 + (threadIdx.x >> 6);
    int row = grp >> 2, nh = grp & 3;
    size_t off = (size_t)row * HH + nh * HD + lane * 2;
    float2 v = *(const float2*)(Yr + off);
    float s = v.x + v.y, ss = v.x * v.x + v.y * v.y;
    for (int o = 32; o > 0; o >>= 1) {
        s  += __shfl_xor(s, o);
        ss += __shfl_xor(ss, o);
    }
    float m   = s * (1.0f / HD);
    float var = ss * (1.0f / HD) - m * m;
    float inv = rsqrtf(var + EPSF);
    int h = nh * HD + lane * 2;
    unsigned gv = *(const unsigned*)(G + off);
    float g0 = bf2f(gv & 0xffff), g1 = bf2f(gv >> 16);
    float2 w2 = *(const float2*)(gw + h), b2 = *(const float2*)(gb + h);
    float yn0 = (v.x - m) * inv * w2.x + b2.x;
    float yn1 = (v.y - m) * inv * w2.y + b2.y;
    float e0v = g0 / (1.0f + expf(-g0)) * yn0;
    float e1v = g1 / (1.0f + expf(-g1)) * yn1;
    *(unsigned*)(E + off) = (unsigned)f2bf(e0v) | ((unsigned)f2bf(e1v) << 16);
}

// ---------------------------------------------------------------- fp32 -> bf16 cast
__global__ __launch_bounds__(256) void k_cast(const float* __restrict__ x, unsigned short* __restrict__ y) {
    size_t i = ((size_t)blockIdx.x * 256 + threadIdx.x) * 8;
    float4 a = *(const float4*)(x + i), c = *(const float4*)(x + i + 4);
    uint4 pk;
    pk.x = f2bf(a.x) | ((unsigned)f2bf(a.y) << 16);
    pk.y = f2bf(a.z) | ((unsigned)f2bf(a.w) << 16);
    pk.z = f2bf(c.x) | ((unsigned)f2bf(c.y) << 16);
    pk.w = f2bf(c.z) | ((unsigned)f2bf(c.w) << 16);
    *(uint4*)(y + i) = pk;
}

// ---------------------------------------------------------------- bf16 MFMA GEMM, 128x128x32, BT weights
// C = A[M][K] * Bt[N][K]^T ; EPI: 0 none | 1 +bias,gelu | 2 +bias+res | 3 +res ; OUTBF: bf16 out
template<int EPI, int OUTBF>
__global__ __launch_bounds__(256) void k_mm(
    const unsigned short* __restrict__ A, const unsigned short* __restrict__ Bt,
    void* __restrict__ Cv, const float* __restrict__ bias, const float* __restrict__ Rs,
    int M, int N, int K, size_t aB, size_t bB, size_t cB) {
    __shared__ __align__(16) char sm[16384];
    const int tid = threadIdx.x;
    const int lane = tid & 63, wid = tid >> 6;
    const int wr = wid >> 1, wc = wid & 1;
    const int lcol = lane & 15, lrow = lane >> 4;
    const size_t m0 = (size_t)blockIdx.x * 128, n0 = (size_t)blockIdx.y * 128;
    const char* Ab = (const char*)(A + (size_t)blockIdx.z * aB);
    const char* Bb = (const char*)(Bt + (size_t)blockIdx.z * bB);
    f32x4 acc[4][4];
    #pragma unroll
    for (int i = 0; i < 4; ++i)
        #pragma unroll
        for (int j = 0; j < 4; ++j) acc[i][j] = f32x4{0.f, 0.f, 0.f, 0.f};
    for (int k0 = 0; k0 < K; k0 += 32) {
        __syncthreads();
        #pragma unroll
        for (int c = 0; c < 2; ++c) {
            int chunk = wid * 2 + c;
            int r = chunk * 16 + (lane >> 2);
            int w = ((lane & 3) ^ (r & 3)) << 4;
            gl16(Ab + ((size_t)(m0 + r) * K + k0) * 2 + w, sm + chunk * 1024);
            gl16(Bb + ((size_t)(n0 + r) * K + k0) * 2 + w, sm + 8192 + chunk * 1024);
        }
        __syncthreads();
        bf16x8 af[4], bfr[4];
        #pragma unroll
        for (int m = 0; m < 4; ++m) {
            int r = wr * 64 + m * 16 + lcol;
            af[m] = ld8(sm + r * 64 + ((lrow * 16) ^ ((r & 3) << 4)));
        }
        #pragma unroll
        for (int n2 = 0; n2 < 4; ++n2) {
            int r = wc * 64 + n2 * 16 + lcol;
            bfr[n2] = ld8(sm + 8192 + r * 64 + ((lrow * 16) ^ ((r & 3) << 4)));
        }
        #pragma unroll
        for (int m = 0; m < 4; ++m)
            #pragma unroll
            for (int n2 = 0; n2 < 4; ++n2)
                acc[m][n2] = __builtin_amdgcn_mfma_f32_16x16x32_bf16(af[m], bfr[n2], acc[m][n2], 0, 0, 0);
    }
    float* Cf = (float*)Cv + (size_t)blockIdx.z * cB;
    unsigned short* Cb = (unsigned short*)Cv + (size_t)blockIdx.z * cB;
    const float* Rb = (EPI >= 2) ? (Rs + (size_t)blockIdx.z * cB) : nullptr;
    #pragma unroll
    for (int m = 0; m < 4; ++m) {
        #pragma unroll
        for (int n2 = 0; n2 < 4; ++n2) {
            size_t col = n0 + wc * 64 + n2 * 16 + lcol;
            float bc = (EPI == 1 || EPI == 2) ? bias[col] : 0.0f;
            #pragma unroll
            for (int j = 0; j < 4; ++j) {
                size_t row = m0 + wr * 64 + m * 16 + lrow * 4 + j;
                float v = acc[m][n2][j];
                if (EPI == 1) { v += bc; v = 0.5f * v * (1.0f + erff(v * 0.70710678118654752f)); }
                else if (EPI == 2) v += bc + Rb[row * N + col];
                else if (EPI == 3) v += Rb[row * N + col];
                if (OUTBF) Cb[row * N + col] = f2bf(v);
                else       Cf[row * N + col] = v;
            }
        }
    }
}

// ---------------------------------------------------------------- launch
extern "C" void kernel_launch(void* const* d_in, const int* in_sizes, int n_in,
                              void* d_out, int out_size, void* d_ws, size_t ws_size,
                              hipStream_t stream) {
    const float* X0  = (const float*)d_in[0];
    const float* WQ  = (const float*)d_in[1];
    const float* WK  = (const float*)d_in[2];
    const float* WV  = (const float*)d_in[3];
    const float* WG  = (const float*)d_in[4];
    const float* WO  = (const float*)d_in[5];
    const float* gnw = (const float*)d_in[6];
    const float* gnb = (const float*)d_in[7];
    const float* l1w = (const float*)d_in[8];
    const float* l1b = (const float*)d_in[9];
    const float* l2w = (const float*)d_in[10];
    const float* l2b = (const float*)d_in[11];
    const float* fw1 = (const float*)d_in[12];
    const float* fb1 = (const float*)d_in[13];
    const float* fw2 = (const float*)d_in[14];
    const float* fb2 = (const float*)d_in[15];
    float* outX = (float*)d_out;
    float* outG = outX + (size_t)ROWS * HH;

    char* wp = (char*)d_ws;
    auto take = [&](size_t bytes) { char* p = wp; wp += (bytes + 255) & ~(size_t)255; return p; };
    float* cq = (float*)take((size_t)SS * HALF * 4);
    float* sq = (float*)take((size_t)SS * HALF * 4);
    float* ck = (float*)take((size_t)SS * HALF * 4);
    float* sk = (float*)take((size_t)SS * HALF * 4);
    unsigned short* WQt = (unsigned short*)take((size_t)NLAYERS * HH * HH * 2);
    unsigned short* WKt = (unsigned short*)take((size_t)NLAYERS * HH * HH * 2);
    unsigned short* WVt = (unsigned short*)take((size_t)NLAYERS * HH * HH * 2);
    unsigned short* WGt = (unsigned short*)take((size_t)NLAYERS * HH * HH * 2);
    unsigned short* WOt = (unsigned short*)take((size_t)NLAYERS * HH * HH * 2);
    unsigned short* F1t = (unsigned short*)take((size_t)NLAYERS * HH * FFND * 2);
    unsigned short* F2t = (unsigned short*)take((size_t)NLAYERS * HH * FFND * 2);
    unsigned short* Xn  = (unsigned short*)take((size_t)ROWS * HH * 2);
    unsigned short* Qb  = (unsigned short*)take((size_t)ROWS * HH * 2);
    unsigned short* Kb  = (unsigned short*)take((size_t)ROWS * HH * 2);
    unsigned short* Vb  = (unsigned short*)take((size_t)ROWS * HH * 2);
    float* Yr   = (float*)take((size_t)ROWS * HH * 4);
    float* Y2   = (float*)take((size_t)ROWS * HH * 4);
    float* Xbuf = (float*)take((size_t)ROWS * HH * 4);
    unsigned short* Hb = (unsigned short*)take((size_t)ROWS * FFND * 2);
    unsigned short* Gb = Kb;   // K dead after retention
    unsigned short* Eb = Qb;   // Q dead after retention
    unsigned short* Xb = Xn;   // reuse for gram cast

    k_tables<<<SS, HALF, 0, stream>>>(cq, sq, ck, sk);
    k_wt<<<dim3(4, 16, 12), 256, 0, stream>>>(WQ, WQt, HH, HD);
    k_wt<<<dim3(4, 16, 12), 256, 0, stream>>>(WK, WKt, HH, HD);
    k_wt<<<dim3(4, 16, 12), 256, 0, stream>>>(WV, WVt, HH, HD);
    k_wt<<<dim3(16, 16, 3), 256, 0, stream>>>(WG, WGt, HH, HH);
    k_wt<<<dim3(16, 16, 3), 256, 0, stream>>>(WO, WOt, HH, HH);
    k_wt<<<dim3(64, 16, 3), 256, 0, stream>>>(fw1, F1t, HH, FFND);
    k_wt<<<dim3(16, 64, 3), 256, 0, stream>>>(fw2, F2t, FFND, HH);

    const float* curX = X0;
    for (int l = 0; l < NLAYERS; ++l) {
        const unsigned short* Bq = WQt + (size_t)l * HH * HH;
        const unsigned short* Bk = WKt + (size_t)l * HH * HH;
        const unsigned short* Bv = WVt + (size_t)l * HH * HH;
        const unsigned short* Bg = WGt + (size_t)l * HH * HH;
        const unsigned short* Bo = WOt + (size_t)l * HH * HH;
        const unsigned short* B1 = F1t + (size_t)l * HH * FFND;
        const unsigned short* B2 = F2t + (size_t)l * HH * FFND;
        k_ln<<<ROWS / 4, 256, 0, stream>>>(curX, l1w + l * HH, l1b + l * HH, Xn);
        dim3 g1(ROWS / 128, HH / 128, 1);
        k_mm<0, 1><<<g1, 256, 0, stream>>>(Xn, Bq, Qb, nullptr, nullptr, ROWS, HH, HH, 0, 0, 0);
        k_mm<0, 1><<<g1, 256, 0, stream>>>(Xn, Bk, Kb, nullptr, nullptr, ROWS, HH, HH, 0, 0, 0);
        k_mm<0, 1><<<g1, 256, 0, stream>>>(Xn, Bv, Vb, nullptr, nullptr, ROWS, HH, HH, 0, 0, 0);
        k_xpos<<<ROWS, 256, 0, stream>>>(Qb, Kb, cq, sq, ck, sk);
        k_ret<<<dim3(SS / 64, NHEADS, BB), 256, 0, stream>>>(Qb, Kb, Vb, Yr);
        k_mm<0, 1><<<g1, 256, 0, stream>>>(Xn, Bg, Gb, nullptr, nullptr, ROWS, HH, HH, 0, 0, 0);
        k_gate<<<ROWS, 256, 0, stream>>>(Yr, Gb, gnw + l * HH, gnb + l * HH, Eb);
        k_mm<3, 0><<<g1, 256, 0, stream>>>(Eb, Bo, Y2, nullptr, curX, ROWS, HH, HH, 0, 0, 0);
        k_ln<<<ROWS / 4, 256, 0, stream>>>(Y2, l2w + l * HH, l2b + l * HH, Xn);
        dim3 g2(ROWS / 128, FFND / 128, 1);
        k_mm<1, 1><<<g2, 256, 0, stream>>>(Xn, B1, Hb, fb1 + (size_t)l * FFND, nullptr, ROWS, FFND, HH, 0, 0, 0);
        float* newX = (l == NLAYERS - 1) ? outX : Xbuf;
        k_mm<2, 0><<<g1, 256, 0, stream>>>(Hb, B2, newX, fb2 + (size_t)l * HH, Y2, ROWS, HH, FFND, 0, 0, 0);
        curX = newX;
    }
    k_cast<<<ROWS * HH / (256 * 8), 256, 0, stream>>>(outX, Xb);
    dim3 g3(SS / 128, SS / 128, BB);
    k_mm<0, 0><<<g3, 256, 0, stream>>>(Xb, Xb, outG, nullptr, nullptr, SS, SS, HH,
                                       (size_t)SS * HH, (size_t)SS * HH, (size_t)SS * SS);
}

// Round 4
// 930.215 us; speedup vs baseline: 5.0919x; 1.1156x over previous
//
#include <hip/hip_runtime.h>
#include <math.h>

#define HH 512
#define NHEADS 4
#define HD 128
#define HALF 64
#define FFND 2048
#define BB 4
#define SS 2048
#define NLAYERS 3
#define ROWS (BB*SS)
#define EPSF 1e-5f
#define QKVGW 2048

typedef float f32x4 __attribute__((ext_vector_type(4)));
typedef float f32x16 __attribute__((ext_vector_type(16)));
typedef __bf16 bf16x8 __attribute__((ext_vector_type(8)));
typedef unsigned u32x2 __attribute__((ext_vector_type(2)));

__device__ __forceinline__ unsigned short f2bf(float f) {
    union { float f; unsigned u; } v; v.f = f;
    unsigned r = (v.u + 0x7FFFu + ((v.u >> 16) & 1u)) >> 16;
    return (unsigned short)r;
}
__device__ __forceinline__ float bf2f(unsigned short h) {
    union { unsigned u; float f; } v; v.u = ((unsigned)h) << 16;
    return v.f;
}
__device__ __forceinline__ void gl16(const void* g, void* l) {
    __builtin_amdgcn_global_load_lds((const __attribute__((address_space(1))) void*)g,
                                     (__attribute__((address_space(3))) void*)l, 16, 0, 0);
}
__device__ __forceinline__ bf16x8 ld8(const void* p) { return *(const bf16x8*)p; }
__device__ __forceinline__ unsigned laddr(void* p) {
    return (unsigned)(size_t)(__attribute__((address_space(3))) char*)p;
}
__device__ __forceinline__ u32x2 tr8(unsigned a) {
    u32x2 r;
    asm volatile("ds_read_b64_tr_b16 %0, %1" : "=v"(r) : "v"(a));
    return r;
}

// ---------------------------------------------------------------- xpos tables
__global__ void k_tables(float* __restrict__ cq, float* __restrict__ sq,
                         float* __restrict__ ck, float* __restrict__ sk) {
    int i = threadIdx.x;
    int s = blockIdx.x;
    float si   = ((float)i + 0.4f * (float)HD) / (1.4f * (float)HD);
    float scale = powf(si, (float)s / 512.0f);
    float invf = powf(10000.0f, -((float)i) / (float)HALF);
    float ang  = (float)s * invf;
    float c = cosf(ang), sn = sinf(ang);
    int idx = s * HALF + i;
    cq[idx] = c * scale;   sq[idx] = sn * scale;
    float is = 1.0f / scale;
    ck[idx] = c * is;      sk[idx] = sn * is;
}

// ---------------------------------------------------------------- weight transpose+cast
// src[K][N] fp32 (batched z: src += z*K*N) -> dst bf16 [N][K] at dst + (z/zn)*sL + (z%zn)*sZ
__global__ __launch_bounds__(256) void k_wt(const float* __restrict__ src, unsigned short* __restrict__ dst,
                                            int K, int N, int zn, size_t sL, size_t sZ) {
    __shared__ float T[32][33];
    int n0 = blockIdx.x * 32, k0 = blockIdx.y * 32;
    int z = blockIdx.z;
    src += (size_t)z * (size_t)K * N;
    dst += (size_t)(z / zn) * sL + (size_t)(z % zn) * sZ;
    int tx = threadIdx.x & 31, ty = threadIdx.x >> 5;
    #pragma unroll
    for (int i = 0; i < 4; ++i) {
        int r = ty + i * 8;
        T[r][tx] = src[(size_t)(k0 + r) * N + n0 + tx];
    }
    __syncthreads();
    #pragma unroll
    for (int i = 0; i < 4; ++i) {
        int r = ty + i * 8;
        dst[(size_t)(n0 + r) * K + k0 + tx] = f2bf(T[tx][r]);
    }
}

// ---------------------------------------------------------------- layernorm fp32 -> bf16
__global__ __launch_bounds__(256) void k_ln(const float* __restrict__ x, const float* __restrict__ w,
                                            const float* __restrict__ b, unsigned short* __restrict__ y) {
    int lane = threadIdx.x & 63;
    size_t row = (size_t)blockIdx.x * 4 + (threadIdx.x >> 6);
    const float4* xr = (const float4*)(x + row * HH);
    float4 v0 = xr[lane * 2];
    float4 v1 = xr[lane * 2 + 1];
    float s  = v0.x + v0.y + v0.z + v0.w + v1.x + v1.y + v1.z + v1.w;
    float ss = v0.x*v0.x + v0.y*v0.y + v0.z*v0.z + v0.w*v0.w
             + v1.x*v1.x + v1.y*v1.y + v1.z*v1.z + v1.w*v1.w;
    for (int off = 32; off > 0; off >>= 1) {
        s  += __shfl_xor(s, off);
        ss += __shfl_xor(ss, off);
    }
    float m   = s * (1.0f / HH);
    float var = ss * (1.0f / HH) - m * m;
    float inv = rsqrtf(var + EPSF);
    int h0 = lane * 8;
    float4 wa = *(const float4*)(w + h0);
    float4 wb = *(const float4*)(w + h0 + 4);
    float4 ba = *(const float4*)(b + h0);
    float4 bb2 = *(const float4*)(b + h0 + 4);
    uint4 pk;
    pk.x = f2bf((v0.x - m) * inv * wa.x + ba.x) | ((unsigned)f2bf((v0.y - m) * inv * wa.y + ba.y) << 16);
    pk.y = f2bf((v0.z - m) * inv * wa.z + ba.z) | ((unsigned)f2bf((v0.w - m) * inv * wa.w + ba.w) << 16);
    pk.z = f2bf((v1.x - m) * inv * wb.x + bb2.x) | ((unsigned)f2bf((v1.y - m) * inv * wb.y + bb2.y) << 16);
    pk.w = f2bf((v1.z - m) * inv * wb.z + bb2.z) | ((unsigned)f2bf((v1.w - m) * inv * wb.w + bb2.w) << 16);
    *(uint4*)(y + row * HH + h0) = pk;
}

// ---------------------------------------------------------------- xpos rotate Q,K inside QKVG
__global__ __launch_bounds__(256) void k_xpos(unsigned short* __restrict__ QG,
    const float* __restrict__ cq, const float* __restrict__ sq,
    const float* __restrict__ ck, const float* __restrict__ sk) {
    int row = blockIdx.x, p = threadIdx.x;
    int s = row & (SS - 1), n = p >> 6, i = p & 63;
    int ti = s * HALF + i;
    size_t qo = (size_t)row * QKVGW + n * HD + i * 2;
    unsigned qv = *(unsigned*)(QG + qo);
    float x1 = bf2f(qv & 0xffff), x2 = bf2f(qv >> 16);
    float c = cq[ti], sn = sq[ti];
    *(unsigned*)(QG + qo) = (unsigned)f2bf(x1 * c - x2 * sn) | ((unsigned)f2bf(x2 * c + x1 * sn) << 16);
    size_t ko = qo + 512;
    unsigned kv = *(unsigned*)(QG + ko);
    x1 = bf2f(kv & 0xffff); x2 = bf2f(kv >> 16);
    c = ck[ti]; sn = sk[ti];
    *(unsigned*)(QG + ko) = (unsigned)f2bf(x1 * c - x2 * sn) | ((unsigned)f2bf(x2 * c + x1 * sn) << 16);
}

// ---------------------------------------------------------------- retention v2
// 2 waves x 32 s-rows, 32x32x16 MFMA, swapped QK (A=K,B=Q), V via subtiled layout + tr_b16 reads.
// LDS: K 0..16K rows [64][256B] xor (r&15)<<4 ; V 16K..32K subtiled [db 0..7][tb 0..15][4][16]
//      P 32K..40K [64 s][64 t] rows 128B xor (s&7)<<4
__global__ __launch_bounds__(128, 2) void k_ret(
    const unsigned short* __restrict__ QG, float* __restrict__ Y) {
    __shared__ __align__(16) char sm[40960];
    const int tid = threadIdx.x;
    const int lane = tid & 63, wv = tid >> 6;
    const int l31 = lane & 31, g2 = lane >> 5;
    const int b4 = (lane >> 4) & 1;
    const int xs = (int)gridDim.x - 1 - (int)blockIdx.x;
    const int hn = blockIdx.y, b = blockIdx.z;
    const int s0 = xs * 64;
    const double la = -3.4657359027997265, lb = -6.238324625039508;
    const float gamma = (float)(1.0 - exp(la + (lb - la) * ((double)hn / 3.0)));
    const float l2g = log2f(gamma);
    const size_t rowbase = (size_t)b * SS;
    const int qcol = hn * HD, kcol = 512 + hn * HD, vcol = 1024 + hn * HD;
    const char* Gp = (const char*)QG;

    // hoisted Q fragments (B operand: col = s row of Q)
    const int srow = s0 + wv * 32 + l31;
    bf16x8 qf[8];
    #pragma unroll
    for (int kc = 0; kc < 8; ++kc)
        qf[kc] = ld8(QG + (rowbase + srow) * QKVGW + qcol + kc * 16 + g2 * 8);

    float gq[4], gj[4];
    #pragma unroll
    for (int q = 0; q < 4; ++q) { gq[q] = exp2f(-l2g * (8.0f * q)); gj[q] = exp2f(-l2g * (float)q); }
    const float gt32m = exp2f(-l2g * 32.0f);

    f32x16 accy[4];
    #pragma unroll
    for (int d = 0; d < 4; ++d)
        #pragma unroll
        for (int e = 0; e < 16; ++e) accy[d][e] = 0.0f;

    const int sloc = wv * 32 + l31;
    const int ssw = (sloc & 7) << 4;
    const int r15 = (l31 & 15) << 4;
    const unsigned vbase = laddr(sm + 16384) + b4 * 2048 + g2 * 256 + (lane & 15) * 2;
    const int nt = xs + 1;

    for (int t = 0; t < nt; ++t) {
        const int t0 = t * 64;
        __syncthreads();
        // K stage: rows [64][256B], source pre-swizzled
        #pragma unroll
        for (int c = 0; c < 8; ++c) {
            int chunk = wv * 8 + c;
            int r = chunk * 4 + (lane >> 4);
            int w = ((lane & 15) * 16) ^ ((r & 15) << 4);
            gl16(Gp + ((rowbase + t0 + r) * QKVGW + kcol) * 2 + w, sm + chunk * 1024);
        }
        // V stage: subtiled [db][tb][4][16], linear dest, per-lane source
        #pragma unroll
        for (int c = 0; c < 8; ++c) {
            int chunk = wv * 8 + c;
            int slot = chunk * 64 + lane;
            int sub = slot >> 3, w8 = slot & 7;
            int db = sub >> 4, tb = sub & 15;
            int tl = tb * 4 + (w8 >> 1);
            int d  = db * 16 + (w8 & 1) * 8;
            gl16(Gp + ((rowbase + t0 + tl) * QKVGW + vcol + d) * 2, sm + 16384 + chunk * 1024);
        }
        __syncthreads();
        // QK^T swapped: pacc[tblk] (rows t, cols s)
        f32x16 pacc0, pacc1;
        #pragma unroll
        for (int e = 0; e < 16; ++e) { pacc0[e] = 0.0f; pacc1[e] = 0.0f; }
        #pragma unroll
        for (int kc = 0; kc < 8; ++kc) {
            bf16x8 k0 = ld8(sm + l31 * 256 + ((kc * 32 + g2 * 16) ^ r15));
            bf16x8 k1 = ld8(sm + (32 + l31) * 256 + ((kc * 32 + g2 * 16) ^ r15));
            pacc0 = __builtin_amdgcn_mfma_f32_32x32x16_bf16(k0, qf[kc], pacc0, 0, 0, 0);
            pacc1 = __builtin_amdgcn_mfma_f32_32x32x16_bf16(k1, qf[kc], pacc1, 0, 0, 0);
        }
        // decay + P store (4 b64 per t-block)
        const float G0 = exp2f(l2g * (float)(srow - t0 - g2 * 4));
        #pragma unroll
        for (int tb2 = 0; tb2 < 2; ++tb2) {
            const float gb = tb2 ? gt32m : 1.0f;
            #pragma unroll
            for (int q = 0; q < 4; ++q) {
                unsigned short u0, u1, u2, u3;
                int tbase = t0 + tb2 * 32 + q * 8 + g2 * 4;
                float base = G0 * gb * gq[q];
                float p0 = (tb2 ? pacc1 : pacc0)[q * 4 + 0];
                float p1 = (tb2 ? pacc1 : pacc0)[q * 4 + 1];
                float p2 = (tb2 ? pacc1 : pacc0)[q * 4 + 2];
                float p3 = (tb2 ? pacc1 : pacc0)[q * 4 + 3];
                u0 = f2bf((srow >= tbase + 0) ? p0 * base * gj[0] : 0.0f);
                u1 = f2bf((srow >= tbase + 1) ? p1 * base * gj[1] : 0.0f);
                u2 = f2bf((srow >= tbase + 2) ? p2 * base * gj[2] : 0.0f);
                u3 = f2bf((srow >= tbase + 3) ? p3 * base * gj[3] : 0.0f);
                u32x2 pk2;
                pk2.x = (unsigned)u0 | ((unsigned)u1 << 16);
                pk2.y = (unsigned)u2 | ((unsigned)u3 << 16);
                *(u32x2*)(sm + 32768 + ((sloc * 128 + tb2 * 64 + q * 16 + g2 * 8) ^ ssw)) = pk2;
            }
        }
        // PV: A = P rows s, B = V cols d via tr reads
        bf16x8 pf[4];
        #pragma unroll
        for (int tc = 0; tc < 4; ++tc)
            pf[tc] = ld8(sm + 32768 + ((sloc * 128 + tc * 32 + g2 * 16) ^ ssw));
        #pragma unroll
        for (int dblk = 0; dblk < 4; ++dblk) {
            u32x2 va[4], vb[4];
            #pragma unroll
            for (int tc = 0; tc < 4; ++tc) {
                unsigned a0 = vbase + dblk * 4096 + tc * 512;
                va[tc] = tr8(a0);
                vb[tc] = tr8(a0 + 128);
            }
            asm volatile("s_waitcnt lgkmcnt(0)" ::: "memory");
            __builtin_amdgcn_sched_barrier(0);
            #pragma unroll
            for (int tc = 0; tc < 4; ++tc) {
                union { u32x2 u[2]; bf16x8 v; } cvt;
                cvt.u[0] = va[tc]; cvt.u[1] = vb[tc];
                accy[dblk] = __builtin_amdgcn_mfma_f32_32x32x16_bf16(pf[tc], cvt.v, accy[dblk], 0, 0, 0);
            }
        }
    }
    // write Y (fp32, [ROWS][HH])
    #pragma unroll
    for (int dblk = 0; dblk < 4; ++dblk)
        #pragma unroll
        for (int rg = 0; rg < 16; ++rg) {
            int sl2 = s0 + wv * 32 + (rg & 3) + (rg >> 2) * 8 + g2 * 4;
            Y[(rowbase + sl2) * HH + hn * HD + dblk * 32 + l31] = accy[dblk][rg];
        }
}

// ---------------------------------------------------------------- groupnorm + silu gate
__global__ __launch_bounds__(256) void k_gate(
    const float* __restrict__ Yr, const unsigned short* __restrict__ QG,
    const float* __restrict__ gw, const float* __restrict__ gb,
    unsigned short* __restrict__ E) {
    int lane = threadIdx.x & 63;
    int grp  = blockIdx.x * 4 + (threadIdx.x >> 6);
    int row = grp >> 2, nh = grp & 3;
    size_t off = (size_t)row * HH + nh * HD + lane * 2;
    float2 v = *(const float2*)(Yr + off);
    float s = v.x + v.y, ss = v.x * v.x + v.y * v.y;
    for (int o = 32; o > 0; o >>= 1) {
        s  += __shfl_xor(s, o);
        ss += __shfl_xor(ss, o);
    }
    float m   = s * (1.0f / HD);
    float var = ss * (1.0f / HD) - m * m;
    float inv = rsqrtf(var + EPSF);
    int h = nh * HD + lane * 2;
    unsigned gv = *(const unsigned*)(QG + (size_t)row * QKVGW + 1536 + nh * HD + lane * 2);
    float g0 = bf2f(gv & 0xffff), g1 = bf2f(gv >> 16);
    float2 w2 = *(const float2*)(gw + h), b2 = *(const float2*)(gb + h);
    float yn0 = (v.x - m) * inv * w2.x + b2.x;
    float yn1 = (v.y - m) * inv * w2.y + b2.y;
    float e0v = g0 / (1.0f + expf(-g0)) * yn0;
    float e1v = g1 / (1.0f + expf(-g1)) * yn1;
    *(unsigned*)(E + off) = (unsigned)f2bf(e0v) | ((unsigned)f2bf(e1v) << 16);
}

// ---------------------------------------------------------------- fp32 -> bf16 cast
__global__ __launch_bounds__(256) void k_cast(const float* __restrict__ x, unsigned short* __restrict__ y) {
    size_t i = ((size_t)blockIdx.x * 256 + threadIdx.x) * 8;
    float4 a = *(const float4*)(x + i), c = *(const float4*)(x + i + 4);
    uint4 pk;
    pk.x = f2bf(a.x) | ((unsigned)f2bf(a.y) << 16);
    pk.y = f2bf(a.z) | ((unsigned)f2bf(a.w) << 16);
    pk.z = f2bf(c.x) | ((unsigned)f2bf(c.y) << 16);
    pk.w = f2bf(c.z) | ((unsigned)f2bf(c.w) << 16);
    *(uint4*)(y + i) = pk;
}

// ---------------------------------------------------------------- bf16 MFMA GEMM 128x128x32 (BT weights)
template<int EPI, int OUTBF>
__global__ __launch_bounds__(256) void k_mm(
    const unsigned short* __restrict__ A, const unsigned short* __restrict__ Bt,
    void* __restrict__ Cv, const float* __restrict__ bias, const float* __restrict__ Rs,
    int M, int N, int K, size_t aB, size_t bB, size_t cB) {
    __shared__ __align__(16) char sm[16384];
    const int tid = threadIdx.x;
    const int lane = tid & 63, wid = tid >> 6;
    const int wr = wid >> 1, wc = wid & 1;
    const int lcol = lane & 15, lrow = lane >> 4;
    const size_t m0 = (size_t)blockIdx.x * 128, n0 = (size_t)blockIdx.y * 128;
    const char* Ab = (const char*)(A + (size_t)blockIdx.z * aB);
    const char* Bb = (const char*)(Bt + (size_t)blockIdx.z * bB);
    f32x4 acc[4][4];
    #pragma unroll
    for (int i = 0; i < 4; ++i)
        #pragma unroll
        for (int j = 0; j < 4; ++j) acc[i][j] = f32x4{0.f, 0.f, 0.f, 0.f};
    for (int k0 = 0; k0 < K; k0 += 32) {
        __syncthreads();
        #pragma unroll
        for (int c = 0; c < 2; ++c) {
            int chunk = wid * 2 + c;
            int r = chunk * 16 + (lane >> 2);
            int w = ((lane & 3) ^ (r & 3)) << 4;
            gl16(Ab + ((size_t)(m0 + r) * K + k0) * 2 + w, sm + chunk * 1024);
            gl16(Bb + ((size_t)(n0 + r) * K + k0) * 2 + w, sm + 8192 + chunk * 1024);
        }
        __syncthreads();
        bf16x8 af[4], bfr[4];
        #pragma unroll
        for (int m = 0; m < 4; ++m) {
            int r = wr * 64 + m * 16 + lcol;
            af[m] = ld8(sm + r * 64 + ((lrow * 16) ^ ((r & 3) << 4)));
        }
        #pragma unroll
        for (int n2 = 0; n2 < 4; ++n2) {
            int r = wc * 64 + n2 * 16 + lcol;
            bfr[n2] = ld8(sm + 8192 + r * 64 + ((lrow * 16) ^ ((r & 3) << 4)));
        }
        #pragma unroll
        for (int m = 0; m < 4; ++m)
            #pragma unroll
            for (int n2 = 0; n2 < 4; ++n2)
                acc[m][n2] = __builtin_amdgcn_mfma_f32_16x16x32_bf16(af[m], bfr[n2], acc[m][n2], 0, 0, 0);
    }
    float* Cf = (float*)Cv + (size_t)blockIdx.z * cB;
    unsigned short* Cb = (unsigned short*)Cv + (size_t)blockIdx.z * cB;
    const float* Rb = (EPI >= 2) ? (Rs + (size_t)blockIdx.z * cB) : nullptr;
    #pragma unroll
    for (int m = 0; m < 4; ++m) {
        #pragma unroll
        for (int n2 = 0; n2 < 4; ++n2) {
            size_t col = n0 + wc * 64 + n2 * 16 + lcol;
            float bc = (EPI == 1 || EPI == 2) ? bias[col] : 0.0f;
            #pragma unroll
            for (int j = 0; j < 4; ++j) {
                size_t row = m0 + wr * 64 + m * 16 + lrow * 4 + j;
                float v = acc[m][n2][j];
                if (EPI == 1) { v += bc; v = 0.5f * v * (1.0f + erff(v * 0.70710678118654752f)); }
                else if (EPI == 2) v += bc + Rb[row * N + col];
                else if (EPI == 3) v += Rb[row * N + col];
                if (OUTBF) Cb[row * N + col] = f2bf(v);
                else       Cf[row * N + col] = v;
            }
        }
    }
}

// ---------------------------------------------------------------- launch
extern "C" void kernel_launch(void* const* d_in, const int* in_sizes, int n_in,
                              void* d_out, int out_size, void* d_ws, size_t ws_size,
                              hipStream_t stream) {
    const float* X0  = (const float*)d_in[0];
    const float* WQ  = (const float*)d_in[1];
    const float* WK  = (const float*)d_in[2];
    const float* WV  = (const float*)d_in[3];
    const float* WG  = (const float*)d_in[4];
    const float* WO  = (const float*)d_in[5];
    const float* gnw = (const float*)d_in[6];
    const float* gnb = (const float*)d_in[7];
    const float* l1w = (const float*)d_in[8];
    const float* l1b = (const float*)d_in[9];
    const float* l2w = (const float*)d_in[10];
    const float* l2b = (const float*)d_in[11];
    const float* fw1 = (const float*)d_in[12];
    const float* fb1 = (const float*)d_in[13];
    const float* fw2 = (const float*)d_in[14];
    const float* fb2 = (const float*)d_in[15];
    float* outX = (float*)d_out;
    float* outG = outX + (size_t)ROWS * HH;

    char* wp = (char*)d_ws;
    auto take = [&](size_t bytes) { char* p = wp; wp += (bytes + 255) & ~(size_t)255; return p; };
    float* cq = (float*)take((size_t)SS * HALF * 4);
    float* sq = (float*)take((size_t)SS * HALF * 4);
    float* ck = (float*)take((size_t)SS * HALF * 4);
    float* sk = (float*)take((size_t)SS * HALF * 4);
    unsigned short* Wcat = (unsigned short*)take((size_t)NLAYERS * QKVGW * HH * 2);
    unsigned short* WOt = (unsigned short*)take((size_t)NLAYERS * HH * HH * 2);
    unsigned short* F1t = (unsigned short*)take((size_t)NLAYERS * HH * FFND * 2);
    unsigned short* F2t = (unsigned short*)take((size_t)NLAYERS * HH * FFND * 2);
    unsigned short* Xn  = (unsigned short*)take((size_t)ROWS * HH * 2);
    unsigned short* QKVG = (unsigned short*)take((size_t)ROWS * QKVGW * 2);
    unsigned short* Eb  = (unsigned short*)take((size_t)ROWS * HH * 2);
    float* Yr   = (float*)take((size_t)ROWS * HH * 4);
    float* Y2   = (float*)take((size_t)ROWS * HH * 4);
    float* Xbuf = (float*)take((size_t)ROWS * HH * 4);
    unsigned short* Hb = (unsigned short*)take((size_t)ROWS * FFND * 2);
    unsigned short* Xb = Xn;

    k_tables<<<SS, HALF, 0, stream>>>(cq, sq, ck, sk);
    // fused QKVG weight panel: rows 0..511 Q (n*128+d), 512..1023 K, 1024..1535 V, 1536..2047 G
    k_wt<<<dim3(4, 16, 12), 256, 0, stream>>>(WQ, Wcat, HH, HD, 4, (size_t)QKVGW * HH, (size_t)HD * HH);
    k_wt<<<dim3(4, 16, 12), 256, 0, stream>>>(WK, Wcat + (size_t)512 * HH, HH, HD, 4, (size_t)QKVGW * HH, (size_t)HD * HH);
    k_wt<<<dim3(4, 16, 12), 256, 0, stream>>>(WV, Wcat + (size_t)1024 * HH, HH, HD, 4, (size_t)QKVGW * HH, (size_t)HD * HH);
    k_wt<<<dim3(16, 16, 3), 256, 0, stream>>>(WG, Wcat + (size_t)1536 * HH, HH, HH, 1, (size_t)QKVGW * HH, 0);
    k_wt<<<dim3(16, 16, 3), 256, 0, stream>>>(WO, WOt, HH, HH, 1, (size_t)HH * HH, 0);
    k_wt<<<dim3(64, 16, 3), 256, 0, stream>>>(fw1, F1t, HH, FFND, 1, (size_t)HH * FFND, 0);
    k_wt<<<dim3(16, 64, 3), 256, 0, stream>>>(fw2, F2t, FFND, HH, 1, (size_t)FFND * HH, 0);

    const float* curX = X0;
    for (int l = 0; l < NLAYERS; ++l) {
        const unsigned short* Bc = Wcat + (size_t)l * QKVGW * HH;
        const unsigned short* Bo = WOt + (size_t)l * HH * HH;
        const unsigned short* B1 = F1t + (size_t)l * HH * FFND;
        const unsigned short* B2 = F2t + (size_t)l * HH * FFND;
        k_ln<<<ROWS / 4, 256, 0, stream>>>(curX, l1w + l * HH, l1b + l * HH, Xn);
        dim3 gq(ROWS / 128, QKVGW / 128, 1);
        k_mm<0, 1><<<gq, 256, 0, stream>>>(Xn, Bc, QKVG, nullptr, nullptr, ROWS, QKVGW, HH, 0, 0, 0);
        k_xpos<<<ROWS, 256, 0, stream>>>(QKVG, cq, sq, ck, sk);
        k_ret<<<dim3(SS / 64, NHEADS, BB), 128, 0, stream>>>(QKVG, Yr);
        k_gate<<<ROWS, 256, 0, stream>>>(Yr, QKVG, gnw + l * HH, gnb + l * HH, Eb);
        dim3 g1(ROWS / 128, HH / 128, 1);
        k_mm<3, 0><<<g1, 256, 0, stream>>>(Eb, Bo, Y2, nullptr, curX, ROWS, HH, HH, 0, 0, 0);
        k_ln<<<ROWS / 4, 256, 0, stream>>>(Y2, l2w + l * HH, l2b + l * HH, Xn);
        dim3 g2(ROWS / 128, FFND / 128, 1);
        k_mm<1, 1><<<g2, 256, 0, stream>>>(Xn, B1, Hb, fb1 + (size_t)l * FFND, nullptr, ROWS, FFND, HH, 0, 0, 0);
        float* newX = (l == NLAYERS - 1) ? outX : Xbuf;
        k_mm<2, 0><<<g1, 256, 0, stream>>>(Hb, B2, newX, fb2 + (size_t)l * HH, Y2, ROWS, HH, FFND, 0, 0, 0);
        curX = newX;
    }
    k_cast<<<ROWS * HH / (256 * 8), 256, 0, stream>>>(outX, Xb);
    dim3 g3(SS / 128, SS / 128, BB);
    k_mm<0, 0><<<g3, 256, 0, stream>>>(Xb, Xb, outG, nullptr, nullptr, SS, SS, HH,
                                       (size_t)SS * HH, (size_t)SS * HH, (size_t)SS * SS);
}

// Round 5
// 893.086 us; speedup vs baseline: 5.3036x; 1.0416x over previous
//
#include <hip/hip_runtime.h>
#include <math.h>

#define HH 512
#define NHEADS 4
#define HD 128
#define HALF 64
#define FFND 2048
#define BB 4
#define SS 2048
#define NLAYERS 3
#define ROWS (BB*SS)
#define EPSF 1e-5f
#define QKVGW 2048

typedef float f32x4 __attribute__((ext_vector_type(4)));
typedef float f32x16 __attribute__((ext_vector_type(16)));
typedef __bf16 bf16x8 __attribute__((ext_vector_type(8)));
typedef unsigned u32x2 __attribute__((ext_vector_type(2)));

__device__ __forceinline__ unsigned short f2bf(float f) {
    union { float f; unsigned u; } v; v.f = f;
    unsigned r = (v.u + 0x7FFFu + ((v.u >> 16) & 1u)) >> 16;
    return (unsigned short)r;
}
__device__ __forceinline__ float bf2f(unsigned short h) {
    union { unsigned u; float f; } v; v.u = ((unsigned)h) << 16;
    return v.f;
}
__device__ __forceinline__ void gl16(const void* g, void* l) {
    __builtin_amdgcn_global_load_lds((const __attribute__((address_space(1))) void*)g,
                                     (__attribute__((address_space(3))) void*)l, 16, 0, 0);
}
__device__ __forceinline__ bf16x8 ld8(const void* p) { return *(const bf16x8*)p; }
__device__ __forceinline__ unsigned laddr(void* p) {
    return (unsigned)(size_t)(__attribute__((address_space(3))) char*)p;
}
__device__ __forceinline__ u32x2 tr8(unsigned a) {
    u32x2 r;
    asm volatile("ds_read_b64_tr_b16 %0, %1" : "=v"(r) : "v"(a));
    return r;
}

// ---------------------------------------------------------------- xpos tables
__global__ void k_tables(float* __restrict__ cq, float* __restrict__ sq,
                         float* __restrict__ ck, float* __restrict__ sk) {
    int i = threadIdx.x;
    int s = blockIdx.x;
    float si   = ((float)i + 0.4f * (float)HD) / (1.4f * (float)HD);
    float scale = powf(si, (float)s / 512.0f);
    float invf = powf(10000.0f, -((float)i) / (float)HALF);
    float ang  = (float)s * invf;
    float c = cosf(ang), sn = sinf(ang);
    int idx = s * HALF + i;
    cq[idx] = c * scale;   sq[idx] = sn * scale;
    float is = 1.0f / scale;
    ck[idx] = c * is;      sk[idx] = sn * is;
}

// ---------------------------------------------------------------- weight transpose+cast
__global__ __launch_bounds__(256) void k_wt(const float* __restrict__ src, unsigned short* __restrict__ dst,
                                            int K, int N, int zn, size_t sL, size_t sZ) {
    __shared__ float T[32][33];
    int n0 = blockIdx.x * 32, k0 = blockIdx.y * 32;
    int z = blockIdx.z;
    src += (size_t)z * (size_t)K * N;
    dst += (size_t)(z / zn) * sL + (size_t)(z % zn) * sZ;
    int tx = threadIdx.x & 31, ty = threadIdx.x >> 5;
    #pragma unroll
    for (int i = 0; i < 4; ++i) {
        int r = ty + i * 8;
        T[r][tx] = src[(size_t)(k0 + r) * N + n0 + tx];
    }
    __syncthreads();
    #pragma unroll
    for (int i = 0; i < 4; ++i) {
        int r = ty + i * 8;
        dst[(size_t)(n0 + r) * K + k0 + tx] = f2bf(T[tx][r]);
    }
}

// ---------------------------------------------------------------- layernorm fp32 -> bf16
__global__ __launch_bounds__(256) void k_ln(const float* __restrict__ x, const float* __restrict__ w,
                                            const float* __restrict__ b, unsigned short* __restrict__ y) {
    int lane = threadIdx.x & 63;
    size_t row = (size_t)blockIdx.x * 4 + (threadIdx.x >> 6);
    const float4* xr = (const float4*)(x + row * HH);
    float4 v0 = xr[lane * 2];
    float4 v1 = xr[lane * 2 + 1];
    float s  = v0.x + v0.y + v0.z + v0.w + v1.x + v1.y + v1.z + v1.w;
    float ss = v0.x*v0.x + v0.y*v0.y + v0.z*v0.z + v0.w*v0.w
             + v1.x*v1.x + v1.y*v1.y + v1.z*v1.z + v1.w*v1.w;
    for (int off = 32; off > 0; off >>= 1) {
        s  += __shfl_xor(s, off);
        ss += __shfl_xor(ss, off);
    }
    float m   = s * (1.0f / HH);
    float var = ss * (1.0f / HH) - m * m;
    float inv = rsqrtf(var + EPSF);
    int h0 = lane * 8;
    float4 wa = *(const float4*)(w + h0);
    float4 wb = *(const float4*)(w + h0 + 4);
    float4 ba = *(const float4*)(b + h0);
    float4 bb2 = *(const float4*)(b + h0 + 4);
    uint4 pk;
    pk.x = f2bf((v0.x - m) * inv * wa.x + ba.x) | ((unsigned)f2bf((v0.y - m) * inv * wa.y + ba.y) << 16);
    pk.y = f2bf((v0.z - m) * inv * wa.z + ba.z) | ((unsigned)f2bf((v0.w - m) * inv * wa.w + ba.w) << 16);
    pk.z = f2bf((v1.x - m) * inv * wb.x + bb2.x) | ((unsigned)f2bf((v1.y - m) * inv * wb.y + bb2.y) << 16);
    pk.w = f2bf((v1.z - m) * inv * wb.z + bb2.z) | ((unsigned)f2bf((v1.w - m) * inv * wb.w + bb2.w) << 16);
    *(uint4*)(y + row * HH + h0) = pk;
}

// ---------------------------------------------------------------- xpos rotate Q,K inside QKVG
__global__ __launch_bounds__(256) void k_xpos(unsigned short* __restrict__ QG,
    const float* __restrict__ cq, const float* __restrict__ sq,
    const float* __restrict__ ck, const float* __restrict__ sk) {
    int row = blockIdx.x, p = threadIdx.x;
    int s = row & (SS - 1), n = p >> 6, i = p & 63;
    int ti = s * HALF + i;
    size_t qo = (size_t)row * QKVGW + n * HD + i * 2;
    unsigned qv = *(unsigned*)(QG + qo);
    float x1 = bf2f(qv & 0xffff), x2 = bf2f(qv >> 16);
    float c = cq[ti], sn = sq[ti];
    *(unsigned*)(QG + qo) = (unsigned)f2bf(x1 * c - x2 * sn) | ((unsigned)f2bf(x2 * c + x1 * sn) << 16);
    size_t ko = qo + 512;
    unsigned kv = *(unsigned*)(QG + ko);
    x1 = bf2f(kv & 0xffff); x2 = bf2f(kv >> 16);
    c = ck[ti]; sn = sk[ti];
    *(unsigned*)(QG + ko) = (unsigned)f2bf(x1 * c - x2 * sn) | ((unsigned)f2bf(x2 * c + x1 * sn) << 16);
}

// ---------------------------------------------------------------- retention v3: split-t + atomic accumulate
// Grid.x = 80 chunk-blocks per (hn,b): each handles <=8 t-tiles of one 64-row s-tile.
// Longest chunks at low blockIdx (launch-order head start). xs<8: plain store; else atomicAdd into zeroed Y.
__global__ __launch_bounds__(128, 2) void k_ret(
    const unsigned short* __restrict__ QG, float* __restrict__ Y) {
    __shared__ __align__(16) char sm[40960];
    const int tid = threadIdx.x;
    const int lane = tid & 63, wv = tid >> 6;
    const int l31 = lane & 31, g2 = lane >> 5;
    const int b4 = (lane >> 4) & 1;
    const int bx = blockIdx.x;
    int xs, c0;
    if (bx < 32)      { xs = 24 + (bx >> 2); c0 = bx & 3; }
    else if (bx < 56) { int i = bx - 32; int d = i / 3; xs = 16 + d; c0 = i - d * 3; }
    else if (bx < 72) { int i = bx - 56; xs = 8 + (i >> 1); c0 = i & 1; }
    else              { xs = bx - 72; c0 = 0; }
    const int hn = blockIdx.y, b = blockIdx.z;
    const int s0 = xs * 64;
    const int tstart = c0 * 8;
    const int tend = min(xs + 1, tstart + 8);
    const double la = -3.4657359027997265, lb = -6.238324625039508;
    const float gamma = (float)(1.0 - exp(la + (lb - la) * ((double)hn / 3.0)));
    const float l2g = log2f(gamma);
    const size_t rowbase = (size_t)b * SS;
    const int qcol = hn * HD, kcol = 512 + hn * HD, vcol = 1024 + hn * HD;
    const char* Gp = (const char*)QG;

    // hoisted Q fragments (B operand: col = s row of Q)
    const int srow = s0 + wv * 32 + l31;
    bf16x8 qf[8];
    #pragma unroll
    for (int kc = 0; kc < 8; ++kc)
        qf[kc] = ld8(QG + (rowbase + srow) * QKVGW + qcol + kc * 16 + g2 * 8);

    float gq[4], gj[4];
    #pragma unroll
    for (int q = 0; q < 4; ++q) { gq[q] = exp2f(-l2g * (8.0f * q)); gj[q] = exp2f(-l2g * (float)q); }
    const float gt32m = exp2f(-l2g * 32.0f);

    f32x16 accy[4];
    #pragma unroll
    for (int d = 0; d < 4; ++d)
        #pragma unroll
        for (int e = 0; e < 16; ++e) accy[d][e] = 0.0f;

    const int sloc = wv * 32 + l31;
    const int ssw = (sloc & 7) << 4;
    const int r15 = (l31 & 15) << 4;
    const unsigned vbase = laddr(sm + 16384) + b4 * 2048 + g2 * 256 + (lane & 15) * 2;

    for (int t = tstart; t < tend; ++t) {
        const int t0 = t * 64;
        __syncthreads();
        // K stage: rows [64][256B], source pre-swizzled
        #pragma unroll
        for (int c = 0; c < 8; ++c) {
            int chunk = wv * 8 + c;
            int r = chunk * 4 + (lane >> 4);
            int w = ((lane & 15) * 16) ^ ((r & 15) << 4);
            gl16(Gp + ((rowbase + t0 + r) * QKVGW + kcol) * 2 + w, sm + chunk * 1024);
        }
        // V stage: subtiled [db][tb][4][16], linear dest, per-lane source
        #pragma unroll
        for (int c = 0; c < 8; ++c) {
            int chunk = wv * 8 + c;
            int slot = chunk * 64 + lane;
            int sub = slot >> 3, w8 = slot & 7;
            int db = sub >> 4, tb = sub & 15;
            int tl = tb * 4 + (w8 >> 1);
            int d  = db * 16 + (w8 & 1) * 8;
            gl16(Gp + ((rowbase + t0 + tl) * QKVGW + vcol + d) * 2, sm + 16384 + chunk * 1024);
        }
        __syncthreads();
        // QK^T swapped: pacc[tblk] (rows t, cols s)
        f32x16 pacc0, pacc1;
        #pragma unroll
        for (int e = 0; e < 16; ++e) { pacc0[e] = 0.0f; pacc1[e] = 0.0f; }
        #pragma unroll
        for (int kc = 0; kc < 8; ++kc) {
            bf16x8 k0 = ld8(sm + l31 * 256 + ((kc * 32 + g2 * 16) ^ r15));
            bf16x8 k1 = ld8(sm + (32 + l31) * 256 + ((kc * 32 + g2 * 16) ^ r15));
            pacc0 = __builtin_amdgcn_mfma_f32_32x32x16_bf16(k0, qf[kc], pacc0, 0, 0, 0);
            pacc1 = __builtin_amdgcn_mfma_f32_32x32x16_bf16(k1, qf[kc], pacc1, 0, 0, 0);
        }
        // decay + P store (4 b64 per t-block)
        const float G0 = exp2f(l2g * (float)(srow - t0 - g2 * 4));
        #pragma unroll
        for (int tb2 = 0; tb2 < 2; ++tb2) {
            const float gb = tb2 ? gt32m : 1.0f;
            #pragma unroll
            for (int q = 0; q < 4; ++q) {
                unsigned short u0, u1, u2, u3;
                int tbase = t0 + tb2 * 32 + q * 8 + g2 * 4;
                float base = G0 * gb * gq[q];
                float p0 = (tb2 ? pacc1 : pacc0)[q * 4 + 0];
                float p1 = (tb2 ? pacc1 : pacc0)[q * 4 + 1];
                float p2 = (tb2 ? pacc1 : pacc0)[q * 4 + 2];
                float p3 = (tb2 ? pacc1 : pacc0)[q * 4 + 3];
                u0 = f2bf((srow >= tbase + 0) ? p0 * base * gj[0] : 0.0f);
                u1 = f2bf((srow >= tbase + 1) ? p1 * base * gj[1] : 0.0f);
                u2 = f2bf((srow >= tbase + 2) ? p2 * base * gj[2] : 0.0f);
                u3 = f2bf((srow >= tbase + 3) ? p3 * base * gj[3] : 0.0f);
                u32x2 pk2;
                pk2.x = (unsigned)u0 | ((unsigned)u1 << 16);
                pk2.y = (unsigned)u2 | ((unsigned)u3 << 16);
                *(u32x2*)(sm + 32768 + ((sloc * 128 + tb2 * 64 + q * 16 + g2 * 8) ^ ssw)) = pk2;
            }
        }
        // PV: A = P rows s, B = V cols d via tr reads
        bf16x8 pf[4];
        #pragma unroll
        for (int tc = 0; tc < 4; ++tc)
            pf[tc] = ld8(sm + 32768 + ((sloc * 128 + tc * 32 + g2 * 16) ^ ssw));
        #pragma unroll
        for (int dblk = 0; dblk < 4; ++dblk) {
            u32x2 va[4], vb[4];
            #pragma unroll
            for (int tc = 0; tc < 4; ++tc) {
                unsigned a0 = vbase + dblk * 4096 + tc * 512;
                va[tc] = tr8(a0);
                vb[tc] = tr8(a0 + 128);
            }
            asm volatile("s_waitcnt lgkmcnt(0)" ::: "memory");
            __builtin_amdgcn_sched_barrier(0);
            #pragma unroll
            for (int tc = 0; tc < 4; ++tc) {
                union { u32x2 u[2]; bf16x8 v; } cvt;
                cvt.u[0] = va[tc]; cvt.u[1] = vb[tc];
                accy[dblk] = __builtin_amdgcn_mfma_f32_32x32x16_bf16(pf[tc], cvt.v, accy[dblk], 0, 0, 0);
            }
        }
    }
    // write Y (fp32): xs<8 has a single chunk -> plain store; else accumulate
    if (xs < 8) {
        #pragma unroll
        for (int dblk = 0; dblk < 4; ++dblk)
            #pragma unroll
            for (int rg = 0; rg < 16; ++rg) {
                int sl2 = s0 + wv * 32 + (rg & 3) + (rg >> 2) * 8 + g2 * 4;
                Y[(rowbase + sl2) * HH + hn * HD + dblk * 32 + l31] = accy[dblk][rg];
            }
    } else {
        #pragma unroll
        for (int dblk = 0; dblk < 4; ++dblk)
            #pragma unroll
            for (int rg = 0; rg < 16; ++rg) {
                int sl2 = s0 + wv * 32 + (rg & 3) + (rg >> 2) * 8 + g2 * 4;
                unsafeAtomicAdd(&Y[(rowbase + sl2) * HH + hn * HD + dblk * 32 + l31], accy[dblk][rg]);
            }
    }
}

// ---------------------------------------------------------------- groupnorm + silu gate
__global__ __launch_bounds__(256) void k_gate(
    const float* __restrict__ Yr, const unsigned short* __restrict__ QG,
    const float* __restrict__ gw, const float* __restrict__ gb,
    unsigned short* __restrict__ E) {
    int lane = threadIdx.x & 63;
    int grp  = blockIdx.x * 4 + (threadIdx.x >> 6);
    int row = grp >> 2, nh = grp & 3;
    size_t off = (size_t)row * HH + nh * HD + lane * 2;
    float2 v = *(const float2*)(Yr + off);
    float s = v.x + v.y, ss = v.x * v.x + v.y * v.y;
    for (int o = 32; o > 0; o >>= 1) {
        s  += __shfl_xor(s, o);
        ss += __shfl_xor(ss, o);
    }
    float m   = s * (1.0f / HD);
    float var = ss * (1.0f / HD) - m * m;
    float inv = rsqrtf(var + EPSF);
    int h = nh * HD + lane * 2;
    unsigned gv = *(const unsigned*)(QG + (size_t)row * QKVGW + 1536 + nh * HD + lane * 2);
    float g0 = bf2f(gv & 0xffff), g1 = bf2f(gv >> 16);
    float2 w2 = *(const float2*)(gw + h), b2 = *(const float2*)(gb + h);
    float yn0 = (v.x - m) * inv * w2.x + b2.x;
    float yn1 = (v.y - m) * inv * w2.y + b2.y;
    float e0v = g0 / (1.0f + expf(-g0)) * yn0;
    float e1v = g1 / (1.0f + expf(-g1)) * yn1;
    *(unsigned*)(E + off) = (unsigned)f2bf(e0v) | ((unsigned)f2bf(e1v) << 16);
}

// ---------------------------------------------------------------- bf16 MFMA GEMM 128x128x32 (BT weights)
// EPI: 0 none | 1 +bias,gelu | 2 +bias+res | 3 +res | 4 +bias+res, dual write (fp32 Cf + bf16 C2)
template<int EPI, int OUTBF>
__global__ __launch_bounds__(256) void k_mm(
    const unsigned short* __restrict__ A, const unsigned short* __restrict__ Bt,
    void* __restrict__ Cv, const float* __restrict__ bias, const float* __restrict__ Rs,
    int M, int N, int K, size_t aB, size_t bB, size_t cB,
    unsigned short* __restrict__ C2) {
    __shared__ __align__(16) char sm[16384];
    const int tid = threadIdx.x;
    const int lane = tid & 63, wid = tid >> 6;
    const int wr = wid >> 1, wc = wid & 1;
    const int lcol = lane & 15, lrow = lane >> 4;
    const size_t m0 = (size_t)blockIdx.x * 128, n0 = (size_t)blockIdx.y * 128;
    const char* Ab = (const char*)(A + (size_t)blockIdx.z * aB);
    const char* Bb = (const char*)(Bt + (size_t)blockIdx.z * bB);
    f32x4 acc[4][4];
    #pragma unroll
    for (int i = 0; i < 4; ++i)
        #pragma unroll
        for (int j = 0; j < 4; ++j) acc[i][j] = f32x4{0.f, 0.f, 0.f, 0.f};
    for (int k0 = 0; k0 < K; k0 += 32) {
        __syncthreads();
        #pragma unroll
        for (int c = 0; c < 2; ++c) {
            int chunk = wid * 2 + c;
            int r = chunk * 16 + (lane >> 2);
            int w = ((lane & 3) ^ (r & 3)) << 4;
            gl16(Ab + ((size_t)(m0 + r) * K + k0) * 2 + w, sm + chunk * 1024);
            gl16(Bb + ((size_t)(n0 + r) * K + k0) * 2 + w, sm + 8192 + chunk * 1024);
        }
        __syncthreads();
        bf16x8 af[4], bfr[4];
        #pragma unroll
        for (int m = 0; m < 4; ++m) {
            int r = wr * 64 + m * 16 + lcol;
            af[m] = ld8(sm + r * 64 + ((lrow * 16) ^ ((r & 3) << 4)));
        }
        #pragma unroll
        for (int n2 = 0; n2 < 4; ++n2) {
            int r = wc * 64 + n2 * 16 + lcol;
            bfr[n2] = ld8(sm + 8192 + r * 64 + ((lrow * 16) ^ ((r & 3) << 4)));
        }
        #pragma unroll
        for (int m = 0; m < 4; ++m)
            #pragma unroll
            for (int n2 = 0; n2 < 4; ++n2)
                acc[m][n2] = __builtin_amdgcn_mfma_f32_16x16x32_bf16(af[m], bfr[n2], acc[m][n2], 0, 0, 0);
    }
    float* Cf = (float*)Cv + (size_t)blockIdx.z * cB;
    unsigned short* Cb = (unsigned short*)Cv + (size_t)blockIdx.z * cB;
    const float* Rb = (EPI >= 2) ? (Rs + (size_t)blockIdx.z * cB) : nullptr;
    #pragma unroll
    for (int m = 0; m < 4; ++m) {
        #pragma unroll
        for (int n2 = 0; n2 < 4; ++n2) {
            size_t col = n0 + wc * 64 + n2 * 16 + lcol;
            float bc = (EPI == 1 || EPI == 2 || EPI == 4) ? bias[col] : 0.0f;
            #pragma unroll
            for (int j = 0; j < 4; ++j) {
                size_t row = m0 + wr * 64 + m * 16 + lrow * 4 + j;
                float v = acc[m][n2][j];
                if (EPI == 1) { v += bc; v = 0.5f * v * (1.0f + erff(v * 0.70710678118654752f)); }
                else if (EPI == 2 || EPI == 4) v += bc + Rb[row * N + col];
                else if (EPI == 3) v += Rb[row * N + col];
                if (EPI == 4) {
                    Cf[row * N + col] = v;
                    C2[row * N + col] = f2bf(v);
                } else if (OUTBF) Cb[row * N + col] = f2bf(v);
                else              Cf[row * N + col] = v;
            }
        }
    }
}

// ---------------------------------------------------------------- launch
extern "C" void kernel_launch(void* const* d_in, const int* in_sizes, int n_in,
                              void* d_out, int out_size, void* d_ws, size_t ws_size,
                              hipStream_t stream) {
    const float* X0  = (const float*)d_in[0];
    const float* WQ  = (const float*)d_in[1];
    const float* WK  = (const float*)d_in[2];
    const float* WV  = (const float*)d_in[3];
    const float* WG  = (const float*)d_in[4];
    const float* WO  = (const float*)d_in[5];
    const float* gnw = (const float*)d_in[6];
    const float* gnb = (const float*)d_in[7];
    const float* l1w = (const float*)d_in[8];
    const float* l1b = (const float*)d_in[9];
    const float* l2w = (const float*)d_in[10];
    const float* l2b = (const float*)d_in[11];
    const float* fw1 = (const float*)d_in[12];
    const float* fb1 = (const float*)d_in[13];
    const float* fw2 = (const float*)d_in[14];
    const float* fb2 = (const float*)d_in[15];
    float* outX = (float*)d_out;
    float* outG = outX + (size_t)ROWS * HH;

    char* wp = (char*)d_ws;
    auto take = [&](size_t bytes) { char* p = wp; wp += (bytes + 255) & ~(size_t)255; return p; };
    float* cq = (float*)take((size_t)SS * HALF * 4);
    float* sq = (float*)take((size_t)SS * HALF * 4);
    float* ck = (float*)take((size_t)SS * HALF * 4);
    float* sk = (float*)take((size_t)SS * HALF * 4);
    unsigned short* Wcat = (unsigned short*)take((size_t)NLAYERS * QKVGW * HH * 2);
    unsigned short* WOt = (unsigned short*)take((size_t)NLAYERS * HH * HH * 2);
    unsigned short* F1t = (unsigned short*)take((size_t)NLAYERS * HH * FFND * 2);
    unsigned short* F2t = (unsigned short*)take((size_t)NLAYERS * HH * FFND * 2);
    unsigned short* Xn  = (unsigned short*)take((size_t)ROWS * HH * 2);
    unsigned short* QKVG = (unsigned short*)take((size_t)ROWS * QKVGW * 2);
    unsigned short* Eb  = (unsigned short*)take((size_t)ROWS * HH * 2);
    float* Yr   = (float*)take((size_t)ROWS * HH * 4);
    float* Y2   = (float*)take((size_t)ROWS * HH * 4);
    float* Xbuf = (float*)take((size_t)ROWS * HH * 4);
    unsigned short* Hb = (unsigned short*)take((size_t)ROWS * FFND * 2);
    unsigned short* Xb = Xn;

    k_tables<<<SS, HALF, 0, stream>>>(cq, sq, ck, sk);
    // fused QKVG weight panel: rows 0..511 Q (n*128+d), 512..1023 K, 1024..1535 V, 1536..2047 G
    k_wt<<<dim3(4, 16, 12), 256, 0, stream>>>(WQ, Wcat, HH, HD, 4, (size_t)QKVGW * HH, (size_t)HD * HH);
    k_wt<<<dim3(4, 16, 12), 256, 0, stream>>>(WK, Wcat + (size_t)512 * HH, HH, HD, 4, (size_t)QKVGW * HH, (size_t)HD * HH);
    k_wt<<<dim3(4, 16, 12), 256, 0, stream>>>(WV, Wcat + (size_t)1024 * HH, HH, HD, 4, (size_t)QKVGW * HH, (size_t)HD * HH);
    k_wt<<<dim3(16, 16, 3), 256, 0, stream>>>(WG, Wcat + (size_t)1536 * HH, HH, HH, 1, (size_t)QKVGW * HH, 0);
    k_wt<<<dim3(16, 16, 3), 256, 0, stream>>>(WO, WOt, HH, HH, 1, (size_t)HH * HH, 0);
    k_wt<<<dim3(64, 16, 3), 256, 0, stream>>>(fw1, F1t, HH, FFND, 1, (size_t)HH * FFND, 0);
    k_wt<<<dim3(16, 64, 3), 256, 0, stream>>>(fw2, F2t, FFND, HH, 1, (size_t)FFND * HH, 0);

    const float* curX = X0;
    for (int l = 0; l < NLAYERS; ++l) {
        const unsigned short* Bc = Wcat + (size_t)l * QKVGW * HH;
        const unsigned short* Bo = WOt + (size_t)l * HH * HH;
        const unsigned short* B1 = F1t + (size_t)l * HH * FFND;
        const unsigned short* B2 = F2t + (size_t)l * HH * FFND;
        k_ln<<<ROWS / 4, 256, 0, stream>>>(curX, l1w + l * HH, l1b + l * HH, Xn);
        dim3 gq(ROWS / 128, QKVGW / 128, 1);
        k_mm<0, 1><<<gq, 256, 0, stream>>>(Xn, Bc, QKVG, nullptr, nullptr, ROWS, QKVGW, HH, 0, 0, 0, nullptr);
        k_xpos<<<ROWS, 256, 0, stream>>>(QKVG, cq, sq, ck, sk);
        hipMemsetAsync(Yr, 0, (size_t)ROWS * HH * 4, stream);
        k_ret<<<dim3(80, NHEADS, BB), 128, 0, stream>>>(QKVG, Yr);
        k_gate<<<ROWS, 256, 0, stream>>>(Yr, QKVG, gnw + l * HH, gnb + l * HH, Eb);
        dim3 g1(ROWS / 128, HH / 128, 1);
        k_mm<3, 0><<<g1, 256, 0, stream>>>(Eb, Bo, Y2, nullptr, curX, ROWS, HH, HH, 0, 0, 0, nullptr);
        k_ln<<<ROWS / 4, 256, 0, stream>>>(Y2, l2w + l * HH, l2b + l * HH, Xn);
        dim3 g2(ROWS / 128, FFND / 128, 1);
        k_mm<1, 1><<<g2, 256, 0, stream>>>(Xn, B1, Hb, fb1 + (size_t)l * FFND, nullptr, ROWS, FFND, HH, 0, 0, 0, nullptr);
        if (l == NLAYERS - 1) {
            k_mm<4, 0><<<g1, 256, 0, stream>>>(Hb, B2, outX, fb2 + (size_t)l * HH, Y2, ROWS, HH, FFND, 0, 0, 0, Xb);
        } else {
            k_mm<2, 0><<<g1, 256, 0, stream>>>(Hb, B2, Xbuf, fb2 + (size_t)l * HH, Y2, ROWS, HH, FFND, 0, 0, 0, nullptr);
        }
        curX = Xbuf;
    }
    dim3 g3(SS / 128, SS / 128, BB);
    k_mm<0, 0><<<g3, 256, 0, stream>>>(Xb, Xb, outG, nullptr, nullptr, SS, SS, HH,
                                       (size_t)SS * HH, (size_t)SS * HH, (size_t)SS * SS, nullptr);
}

// Round 6
// 870.498 us; speedup vs baseline: 5.4412x; 1.0259x over previous
//
#include <hip/hip_runtime.h>
#include <math.h>

#define HH 512
#define NHEADS 4
#define HD 128
#define HALF 64
#define FFND 2048
#define BB 4
#define SS 2048
#define NLAYERS 3
#define ROWS (BB*SS)
#define EPSF 1e-5f
#define QKVGW 2048

typedef float f32x4 __attribute__((ext_vector_type(4)));
typedef float f32x16 __attribute__((ext_vector_type(16)));
typedef __bf16 bf16x8 __attribute__((ext_vector_type(8)));
typedef unsigned u32x2 __attribute__((ext_vector_type(2)));

__device__ __forceinline__ unsigned short f2bf(float f) {
    union { float f; unsigned u; } v; v.f = f;
    unsigned r = (v.u + 0x7FFFu + ((v.u >> 16) & 1u)) >> 16;
    return (unsigned short)r;
}
__device__ __forceinline__ float bf2f(unsigned short h) {
    union { unsigned u; float f; } v; v.u = ((unsigned)h) << 16;
    return v.f;
}
__device__ __forceinline__ void gl16(const void* g, void* l) {
    __builtin_amdgcn_global_load_lds((const __attribute__((address_space(1))) void*)g,
                                     (__attribute__((address_space(3))) void*)l, 16, 0, 0);
}
__device__ __forceinline__ bf16x8 ld8(const void* p) { return *(const bf16x8*)p; }
__device__ __forceinline__ unsigned laddr(void* p) {
    return (unsigned)(size_t)(__attribute__((address_space(3))) char*)p;
}
__device__ __forceinline__ u32x2 tr8(unsigned a) {
    u32x2 r;
    asm volatile("ds_read_b64_tr_b16 %0, %1" : "=v"(r) : "v"(a));
    return r;
}

// ---------------------------------------------------------------- xpos tables
__global__ void k_tables(float* __restrict__ cq, float* __restrict__ sq,
                         float* __restrict__ ck, float* __restrict__ sk) {
    int i = threadIdx.x;
    int s = blockIdx.x;
    float si   = ((float)i + 0.4f * (float)HD) / (1.4f * (float)HD);
    float scale = powf(si, (float)s / 512.0f);
    float invf = powf(10000.0f, -((float)i) / (float)HALF);
    float ang  = (float)s * invf;
    float c = cosf(ang), sn = sinf(ang);
    int idx = s * HALF + i;
    cq[idx] = c * scale;   sq[idx] = sn * scale;
    float is = 1.0f / scale;
    ck[idx] = c * is;      sk[idx] = sn * is;
}

// ---------------------------------------------------------------- weight transpose+cast
__global__ __launch_bounds__(256) void k_wt(const float* __restrict__ src, unsigned short* __restrict__ dst,
                                            int K, int N, int zn, size_t sL, size_t sZ) {
    __shared__ float T[32][33];
    int n0 = blockIdx.x * 32, k0 = blockIdx.y * 32;
    int z = blockIdx.z;
    src += (size_t)z * (size_t)K * N;
    dst += (size_t)(z / zn) * sL + (size_t)(z % zn) * sZ;
    int tx = threadIdx.x & 31, ty = threadIdx.x >> 5;
    #pragma unroll
    for (int i = 0; i < 4; ++i) {
        int r = ty + i * 8;
        T[r][tx] = src[(size_t)(k0 + r) * N + n0 + tx];
    }
    __syncthreads();
    #pragma unroll
    for (int i = 0; i < 4; ++i) {
        int r = ty + i * 8;
        dst[(size_t)(n0 + r) * K + k0 + tx] = f2bf(T[tx][r]);
    }
}

// ---------------------------------------------------------------- layernorm fp32 -> bf16
__global__ __launch_bounds__(256) void k_ln(const float* __restrict__ x, const float* __restrict__ w,
                                            const float* __restrict__ b, unsigned short* __restrict__ y) {
    int lane = threadIdx.x & 63;
    size_t row = (size_t)blockIdx.x * 4 + (threadIdx.x >> 6);
    const float4* xr = (const float4*)(x + row * HH);
    float4 v0 = xr[lane * 2];
    float4 v1 = xr[lane * 2 + 1];
    float s  = v0.x + v0.y + v0.z + v0.w + v1.x + v1.y + v1.z + v1.w;
    float ss = v0.x*v0.x + v0.y*v0.y + v0.z*v0.z + v0.w*v0.w
             + v1.x*v1.x + v1.y*v1.y + v1.z*v1.z + v1.w*v1.w;
    for (int off = 32; off > 0; off >>= 1) {
        s  += __shfl_xor(s, off);
        ss += __shfl_xor(ss, off);
    }
    float m   = s * (1.0f / HH);
    float var = ss * (1.0f / HH) - m * m;
    float inv = rsqrtf(var + EPSF);
    int h0 = lane * 8;
    float4 wa = *(const float4*)(w + h0);
    float4 wb = *(const float4*)(w + h0 + 4);
    float4 ba = *(const float4*)(b + h0);
    float4 bb2 = *(const float4*)(b + h0 + 4);
    uint4 pk;
    pk.x = f2bf((v0.x - m) * inv * wa.x + ba.x) | ((unsigned)f2bf((v0.y - m) * inv * wa.y + ba.y) << 16);
    pk.y = f2bf((v0.z - m) * inv * wa.z + ba.z) | ((unsigned)f2bf((v0.w - m) * inv * wa.w + ba.w) << 16);
    pk.z = f2bf((v1.x - m) * inv * wb.x + bb2.x) | ((unsigned)f2bf((v1.y - m) * inv * wb.y + bb2.y) << 16);
    pk.w = f2bf((v1.z - m) * inv * wb.z + bb2.z) | ((unsigned)f2bf((v1.w - m) * inv * wb.w + bb2.w) << 16);
    *(uint4*)(y + row * HH + h0) = pk;
}

// ---------------------------------------------------------------- xpos rotate Q,K inside QKVG
__global__ __launch_bounds__(256) void k_xpos(unsigned short* __restrict__ QG,
    const float* __restrict__ cq, const float* __restrict__ sq,
    const float* __restrict__ ck, const float* __restrict__ sk) {
    int row = blockIdx.x, p = threadIdx.x;
    int s = row & (SS - 1), n = p >> 6, i = p & 63;
    int ti = s * HALF + i;
    size_t qo = (size_t)row * QKVGW + n * HD + i * 2;
    unsigned qv = *(unsigned*)(QG + qo);
    float x1 = bf2f(qv & 0xffff), x2 = bf2f(qv >> 16);
    float c = cq[ti], sn = sq[ti];
    *(unsigned*)(QG + qo) = (unsigned)f2bf(x1 * c - x2 * sn) | ((unsigned)f2bf(x2 * c + x1 * sn) << 16);
    size_t ko = qo + 512;
    unsigned kv = *(unsigned*)(QG + ko);
    x1 = bf2f(kv & 0xffff); x2 = bf2f(kv >> 16);
    c = ck[ti]; sn = sk[ti];
    *(unsigned*)(QG + ko) = (unsigned)f2bf(x1 * c - x2 * sn) | ((unsigned)f2bf(x2 * c + x1 * sn) << 16);
}

// ---------------------------------------------------------------- zero the atomic-accumulated Y region (rows 512.. per batch)
__global__ __launch_bounds__(256) void k_zero(float* __restrict__ Y) {
    int idx = blockIdx.x * 256 + threadIdx.x;          // 0..786431 float4s
    int bb = idx / 196608;
    int rem = idx - bb * 196608;
    float4 zz = {0.f, 0.f, 0.f, 0.f};
    *(float4*)(Y + (size_t)bb * (SS * HH) + (size_t)512 * HH + (size_t)rem * 4) = zz;
}

// ---------------------------------------------------------------- retention v4: 4-wave, 128-row s-tile, dbuf K/V, counted vmcnt
// Grid.x = 40 chunks per (hn,b). s-tile = 128 rows (4 waves x 32). nt = 2*xs+2 t-tiles of 64.
// LDS: K0 0..16K, K1 16..32K, V0 32..48K, V1 48..64K (subtiled), P 64..80K (128 rows x 128B, xor (r&7)<<4)
__global__ __launch_bounds__(256, 2) void k_ret(
    const unsigned short* __restrict__ QG, float* __restrict__ Y) {
    __shared__ __align__(16) char sm[81920];
    const int tid = threadIdx.x;
    const int lane = tid & 63, wv = tid >> 6;
    const int l31 = lane & 31, g2 = lane >> 5;
    const int b4 = (lane >> 4) & 1;
    const int bx = blockIdx.x;
    int xs, c0 = 0;
    if (bx < 16)      { xs = 15 - (bx >> 2); c0 = bx & 3; }
    else if (bx < 28) { int i = bx - 16; xs = 11 - i / 3; c0 = i % 3; }
    else if (bx < 36) { int i = bx - 28; xs = 7 - (i >> 1); c0 = i & 1; }
    else              { xs = 39 - bx; }
    const int hn = blockIdx.y, b = blockIdx.z;
    const int s0 = xs * 128;
    const int nt = 2 * xs + 2;
    const int tstart = c0 * 8;
    const int tend = min(nt, tstart + 8);
    const double la = -3.4657359027997265, lb = -6.238324625039508;
    const float gamma = (float)(1.0 - exp(la + (lb - la) * ((double)hn / 3.0)));
    const float l2g = log2f(gamma);
    const size_t rowbase = (size_t)b * SS;
    const int qcol = hn * HD, kcol = 512 + hn * HD, vcol = 1024 + hn * HD;
    const char* Gp = (const char*)QG;

    // hoisted Q fragments (B operand: col = s row of Q)
    const int srow = s0 + wv * 32 + l31;
    bf16x8 qf[8];
    #pragma unroll
    for (int kc = 0; kc < 8; ++kc)
        qf[kc] = ld8(QG + (rowbase + srow) * QKVGW + qcol + kc * 16 + g2 * 8);

    float gq[4], gj[4];
    #pragma unroll
    for (int q = 0; q < 4; ++q) { gq[q] = exp2f(-l2g * (8.0f * q)); gj[q] = exp2f(-l2g * (float)q); }
    const float gt32m = exp2f(-l2g * 32.0f);

    f32x16 accy[4];
    #pragma unroll
    for (int d = 0; d < 4; ++d)
        #pragma unroll
        for (int e = 0; e < 16; ++e) accy[d][e] = 0.0f;

    const int sloc = wv * 32 + l31;          // 0..127
    const int ssw = (sloc & 7) << 4;
    const int r15 = (l31 & 15) << 4;

    auto stage = [&](int t0, int buf) {
        #pragma unroll
        for (int c = 0; c < 4; ++c) {
            int chunk = wv * 4 + c;
            int r = chunk * 4 + (lane >> 4);
            int w = ((lane & 15) * 16) ^ ((r & 15) << 4);
            gl16(Gp + ((rowbase + t0 + r) * QKVGW + kcol) * 2 + w, sm + buf * 16384 + chunk * 1024);
        }
        #pragma unroll
        for (int c = 0; c < 4; ++c) {
            int chunk = wv * 4 + c;
            int slot = chunk * 64 + lane;
            int sub = slot >> 3, w8 = slot & 7;
            int db = sub >> 4, tb = sub & 15;
            int tl = tb * 4 + (w8 >> 1);
            int d  = db * 16 + (w8 & 1) * 8;
            gl16(Gp + ((rowbase + t0 + tl) * QKVGW + vcol + d) * 2, sm + 32768 + buf * 16384 + chunk * 1024);
        }
    };

    int cur = 0;
    stage(tstart * 64, 0);
    for (int t = tstart; t < tend; ++t) {
        const int t0 = t * 64;
        if (t + 1 < tend) {
            stage((t + 1) * 64, cur ^ 1);
            asm volatile("s_waitcnt vmcnt(8)" ::: "memory");
        } else {
            asm volatile("s_waitcnt vmcnt(0)" ::: "memory");
        }
        __builtin_amdgcn_sched_barrier(0);
        __builtin_amdgcn_s_barrier();        // cur K/V visible to all waves
        __builtin_amdgcn_sched_barrier(0);
        {
            const char* kb = sm + cur * 16384;
            f32x16 pacc0, pacc1;
            #pragma unroll
            for (int e = 0; e < 16; ++e) { pacc0[e] = 0.0f; pacc1[e] = 0.0f; }
            #pragma unroll
            for (int kc = 0; kc < 8; ++kc) {
                bf16x8 k0 = ld8(kb + l31 * 256 + ((kc * 32 + g2 * 16) ^ r15));
                bf16x8 k1 = ld8(kb + (32 + l31) * 256 + ((kc * 32 + g2 * 16) ^ r15));
                pacc0 = __builtin_amdgcn_mfma_f32_32x32x16_bf16(k0, qf[kc], pacc0, 0, 0, 0);
                pacc1 = __builtin_amdgcn_mfma_f32_32x32x16_bf16(k1, qf[kc], pacc1, 0, 0, 0);
            }
            // decay + P store (bf16, 4 b64 per t-block)
            const float G0 = exp2f(l2g * (float)(srow - t0 - g2 * 4));
            #pragma unroll
            for (int tb2 = 0; tb2 < 2; ++tb2) {
                const float gb = tb2 ? gt32m : 1.0f;
                #pragma unroll
                for (int q = 0; q < 4; ++q) {
                    int tbase = t0 + tb2 * 32 + q * 8 + g2 * 4;
                    float base = G0 * gb * gq[q];
                    float p0 = (tb2 ? pacc1 : pacc0)[q * 4 + 0];
                    float p1 = (tb2 ? pacc1 : pacc0)[q * 4 + 1];
                    float p2 = (tb2 ? pacc1 : pacc0)[q * 4 + 2];
                    float p3 = (tb2 ? pacc1 : pacc0)[q * 4 + 3];
                    unsigned short u0 = f2bf((srow >= tbase + 0) ? p0 * base * gj[0] : 0.0f);
                    unsigned short u1 = f2bf((srow >= tbase + 1) ? p1 * base * gj[1] : 0.0f);
                    unsigned short u2 = f2bf((srow >= tbase + 2) ? p2 * base * gj[2] : 0.0f);
                    unsigned short u3 = f2bf((srow >= tbase + 3) ? p3 * base * gj[3] : 0.0f);
                    u32x2 pk2;
                    pk2.x = (unsigned)u0 | ((unsigned)u1 << 16);
                    pk2.y = (unsigned)u2 | ((unsigned)u3 << 16);
                    *(u32x2*)(sm + 65536 + ((sloc * 128 + tb2 * 64 + q * 16 + g2 * 8) ^ ssw)) = pk2;
                }
            }
            // PV: A = P rows s, B = V cols d via tr reads
            bf16x8 pf[4];
            #pragma unroll
            for (int tc = 0; tc < 4; ++tc)
                pf[tc] = ld8(sm + 65536 + ((sloc * 128 + tc * 32 + g2 * 16) ^ ssw));
            const unsigned vbase = laddr(sm + 32768 + cur * 16384) + b4 * 2048 + g2 * 256 + (lane & 15) * 2;
            #pragma unroll
            for (int dblk = 0; dblk < 4; ++dblk) {
                u32x2 va[4], vb[4];
                #pragma unroll
                for (int tc = 0; tc < 4; ++tc) {
                    unsigned a0 = vbase + dblk * 4096 + tc * 512;
                    va[tc] = tr8(a0);
                    vb[tc] = tr8(a0 + 128);
                }
                asm volatile("s_waitcnt lgkmcnt(0)" ::: "memory");
                __builtin_amdgcn_sched_barrier(0);
                #pragma unroll
                for (int tc = 0; tc < 4; ++tc) {
                    union { u32x2 u[2]; bf16x8 v; } cvt;
                    cvt.u[0] = va[tc]; cvt.u[1] = vb[tc];
                    accy[dblk] = __builtin_amdgcn_mfma_f32_32x32x16_bf16(pf[tc], cvt.v, accy[dblk], 0, 0, 0);
                }
            }
        }
        __builtin_amdgcn_sched_barrier(0);
        __builtin_amdgcn_s_barrier();        // all waves done reading cur
        __builtin_amdgcn_sched_barrier(0);
        cur ^= 1;
    }
    // write Y (fp32): xs<4 is single-chunk -> plain store; else accumulate into zeroed Y
    if (xs < 4) {
        #pragma unroll
        for (int dblk = 0; dblk < 4; ++dblk)
            #pragma unroll
            for (int rg = 0; rg < 16; ++rg) {
                int sl2 = s0 + wv * 32 + (rg & 3) + (rg >> 2) * 8 + g2 * 4;
                Y[(rowbase + sl2) * HH + hn * HD + dblk * 32 + l31] = accy[dblk][rg];
            }
    } else {
        #pragma unroll
        for (int dblk = 0; dblk < 4; ++dblk)
            #pragma unroll
            for (int rg = 0; rg < 16; ++rg) {
                int sl2 = s0 + wv * 32 + (rg & 3) + (rg >> 2) * 8 + g2 * 4;
                unsafeAtomicAdd(&Y[(rowbase + sl2) * HH + hn * HD + dblk * 32 + l31], accy[dblk][rg]);
            }
    }
}

// ---------------------------------------------------------------- groupnorm + silu gate
__global__ __launch_bounds__(256) void k_gate(
    const float* __restrict__ Yr, const unsigned short* __restrict__ QG,
    const float* __restrict__ gw, const float* __restrict__ gb,
    unsigned short* __restrict__ E) {
    int lane = threadIdx.x & 63;
    int grp  = blockIdx.x * 4 + (threadIdx.x >> 6);
    int row = grp >> 2, nh = grp & 3;
    size_t off = (size_t)row * HH + nh * HD + lane * 2;
    float2 v = *(const float2*)(Yr + off);
    float s = v.x + v.y, ss = v.x * v.x + v.y * v.y;
    for (int o = 32; o > 0; o >>= 1) {
        s  += __shfl_xor(s, o);
        ss += __shfl_xor(ss, o);
    }
    float m   = s * (1.0f / HD);
    float var = ss * (1.0f / HD) - m * m;
    float inv = rsqrtf(var + EPSF);
    int h = nh * HD + lane * 2;
    unsigned gv = *(const unsigned*)(QG + (size_t)row * QKVGW + 1536 + nh * HD + lane * 2);
    float g0 = bf2f(gv & 0xffff), g1 = bf2f(gv >> 16);
    float2 w2 = *(const float2*)(gw + h), b2 = *(const float2*)(gb + h);
    float yn0 = (v.x - m) * inv * w2.x + b2.x;
    float yn1 = (v.y - m) * inv * w2.y + b2.y;
    float e0v = g0 / (1.0f + expf(-g0)) * yn0;
    float e1v = g1 / (1.0f + expf(-g1)) * yn1;
    *(unsigned*)(E + off) = (unsigned)f2bf(e0v) | ((unsigned)f2bf(e1v) << 16);
}

// ---------------------------------------------------------------- bf16 MFMA GEMM 128x128x32 (BT weights)
// EPI: 0 none | 1 +bias,gelu | 2 +bias+res | 3 +res | 4 +bias+res, dual write (fp32 Cf + bf16 C2)
template<int EPI, int OUTBF>
__global__ __launch_bounds__(256) void k_mm(
    const unsigned short* __restrict__ A, const unsigned short* __restrict__ Bt,
    void* __restrict__ Cv, const float* __restrict__ bias, const float* __restrict__ Rs,
    int M, int N, int K, size_t aB, size_t bB, size_t cB,
    unsigned short* __restrict__ C2) {
    __shared__ __align__(16) char sm[16384];
    const int tid = threadIdx.x;
    const int lane = tid & 63, wid = tid >> 6;
    const int wr = wid >> 1, wc = wid & 1;
    const int lcol = lane & 15, lrow = lane >> 4;
    const size_t m0 = (size_t)blockIdx.x * 128, n0 = (size_t)blockIdx.y * 128;
    const char* Ab = (const char*)(A + (size_t)blockIdx.z * aB);
    const char* Bb = (const char*)(Bt + (size_t)blockIdx.z * bB);
    f32x4 acc[4][4];
    #pragma unroll
    for (int i = 0; i < 4; ++i)
        #pragma unroll
        for (int j = 0; j < 4; ++j) acc[i][j] = f32x4{0.f, 0.f, 0.f, 0.f};
    for (int k0 = 0; k0 < K; k0 += 32) {
        __syncthreads();
        #pragma unroll
        for (int c = 0; c < 2; ++c) {
            int chunk = wid * 2 + c;
            int r = chunk * 16 + (lane >> 2);
            int w = ((lane & 3) ^ (r & 3)) << 4;
            gl16(Ab + ((size_t)(m0 + r) * K + k0) * 2 + w, sm + chunk * 1024);
            gl16(Bb + ((size_t)(n0 + r) * K + k0) * 2 + w, sm + 8192 + chunk * 1024);
        }
        __syncthreads();
        bf16x8 af[4], bfr[4];
        #pragma unroll
        for (int m = 0; m < 4; ++m) {
            int r = wr * 64 + m * 16 + lcol;
            af[m] = ld8(sm + r * 64 + ((lrow * 16) ^ ((r & 3) << 4)));
        }
        #pragma unroll
        for (int n2 = 0; n2 < 4; ++n2) {
            int r = wc * 64 + n2 * 16 + lcol;
            bfr[n2] = ld8(sm + 8192 + r * 64 + ((lrow * 16) ^ ((r & 3) << 4)));
        }
        #pragma unroll
        for (int m = 0; m < 4; ++m)
            #pragma unroll
            for (int n2 = 0; n2 < 4; ++n2)
                acc[m][n2] = __builtin_amdgcn_mfma_f32_16x16x32_bf16(af[m], bfr[n2], acc[m][n2], 0, 0, 0);
    }
    float* Cf = (float*)Cv + (size_t)blockIdx.z * cB;
    unsigned short* Cb = (unsigned short*)Cv + (size_t)blockIdx.z * cB;
    const float* Rb = (EPI >= 2) ? (Rs + (size_t)blockIdx.z * cB) : nullptr;
    #pragma unroll
    for (int m = 0; m < 4; ++m) {
        #pragma unroll
        for (int n2 = 0; n2 < 4; ++n2) {
            size_t col = n0 + wc * 64 + n2 * 16 + lcol;
            float bc = (EPI == 1 || EPI == 2 || EPI == 4) ? bias[col] : 0.0f;
            #pragma unroll
            for (int j = 0; j < 4; ++j) {
                size_t row = m0 + wr * 64 + m * 16 + lrow * 4 + j;
                float v = acc[m][n2][j];
                if (EPI == 1) { v += bc; v = 0.5f * v * (1.0f + erff(v * 0.70710678118654752f)); }
                else if (EPI == 2 || EPI == 4) v += bc + Rb[row * N + col];
                else if (EPI == 3) v += Rb[row * N + col];
                if (EPI == 4) {
                    Cf[row * N + col] = v;
                    C2[row * N + col] = f2bf(v);
                } else if (OUTBF) Cb[row * N + col] = f2bf(v);
                else              Cf[row * N + col] = v;
            }
        }
    }
}

// ---------------------------------------------------------------- launch
extern "C" void kernel_launch(void* const* d_in, const int* in_sizes, int n_in,
                              void* d_out, int out_size, void* d_ws, size_t ws_size,
                              hipStream_t stream) {
    const float* X0  = (const float*)d_in[0];
    const float* WQ  = (const float*)d_in[1];
    const float* WK  = (const float*)d_in[2];
    const float* WV  = (const float*)d_in[3];
    const float* WG  = (const float*)d_in[4];
    const float* WO  = (const float*)d_in[5];
    const float* gnw = (const float*)d_in[6];
    const float* gnb = (const float*)d_in[7];
    const float* l1w = (const float*)d_in[8];
    const float* l1b = (const float*)d_in[9];
    const float* l2w = (const float*)d_in[10];
    const float* l2b = (const float*)d_in[11];
    const float* fw1 = (const float*)d_in[12];
    const float* fb1 = (const float*)d_in[13];
    const float* fw2 = (const float*)d_in[14];
    const float* fb2 = (const float*)d_in[15];
    float* outX = (float*)d_out;
    float* outG = outX + (size_t)ROWS * HH;

    char* wp = (char*)d_ws;
    auto take = [&](size_t bytes) { char* p = wp; wp += (bytes + 255) & ~(size_t)255; return p; };
    float* cq = (float*)take((size_t)SS * HALF * 4);
    float* sq = (float*)take((size_t)SS * HALF * 4);
    float* ck = (float*)take((size_t)SS * HALF * 4);
    float* sk = (float*)take((size_t)SS * HALF * 4);
    unsigned short* Wcat = (unsigned short*)take((size_t)NLAYERS * QKVGW * HH * 2);
    unsigned short* WOt = (unsigned short*)take((size_t)NLAYERS * HH * HH * 2);
    unsigned short* F1t = (unsigned short*)take((size_t)NLAYERS * HH * FFND * 2);
    unsigned short* F2t = (unsigned short*)take((size_t)NLAYERS * HH * FFND * 2);
    unsigned short* Xn  = (unsigned short*)take((size_t)ROWS * HH * 2);
    unsigned short* QKVG = (unsigned short*)take((size_t)ROWS * QKVGW * 2);
    unsigned short* Eb  = (unsigned short*)take((size_t)ROWS * HH * 2);
    float* Yr   = (float*)take((size_t)ROWS * HH * 4);
    float* Y2   = (float*)take((size_t)ROWS * HH * 4);
    float* Xbuf = (float*)take((size_t)ROWS * HH * 4);
    unsigned short* Hb = (unsigned short*)take((size_t)ROWS * FFND * 2);
    unsigned short* Xb = Xn;

    k_tables<<<SS, HALF, 0, stream>>>(cq, sq, ck, sk);
    // fused QKVG weight panel: rows 0..511 Q (n*128+d), 512..1023 K, 1024..1535 V, 1536..2047 G
    k_wt<<<dim3(4, 16, 12), 256, 0, stream>>>(WQ, Wcat, HH, HD, 4, (size_t)QKVGW * HH, (size_t)HD * HH);
    k_wt<<<dim3(4, 16, 12), 256, 0, stream>>>(WK, Wcat + (size_t)512 * HH, HH, HD, 4, (size_t)QKVGW * HH, (size_t)HD * HH);
    k_wt<<<dim3(4, 16, 12), 256, 0, stream>>>(WV, Wcat + (size_t)1024 * HH, HH, HD, 4, (size_t)QKVGW * HH, (size_t)HD * HH);
    k_wt<<<dim3(16, 16, 3), 256, 0, stream>>>(WG, Wcat + (size_t)1536 * HH, HH, HH, 1, (size_t)QKVGW * HH, 0);
    k_wt<<<dim3(16, 16, 3), 256, 0, stream>>>(WO, WOt, HH, HH, 1, (size_t)HH * HH, 0);
    k_wt<<<dim3(64, 16, 3), 256, 0, stream>>>(fw1, F1t, HH, FFND, 1, (size_t)HH * FFND, 0);
    k_wt<<<dim3(16, 64, 3), 256, 0, stream>>>(fw2, F2t, FFND, HH, 1, (size_t)FFND * HH, 0);

    const float* curX = X0;
    for (int l = 0; l < NLAYERS; ++l) {
        const unsigned short* Bc = Wcat + (size_t)l * QKVGW * HH;
        const unsigned short* Bo = WOt + (size_t)l * HH * HH;
        const unsigned short* B1 = F1t + (size_t)l * HH * FFND;
        const unsigned short* B2 = F2t + (size_t)l * HH * FFND;
        k_ln<<<ROWS / 4, 256, 0, stream>>>(curX, l1w + l * HH, l1b + l * HH, Xn);
        dim3 gq(ROWS / 128, QKVGW / 128, 1);
        k_mm<0, 1><<<gq, 256, 0, stream>>>(Xn, Bc, QKVG, nullptr, nullptr, ROWS, QKVGW, HH, 0, 0, 0, nullptr);
        k_xpos<<<ROWS, 256, 0, stream>>>(QKVG, cq, sq, ck, sk);
        k_zero<<<3072, 256, 0, stream>>>(Yr);
        k_ret<<<dim3(40, NHEADS, BB), 256, 0, stream>>>(QKVG, Yr);
        k_gate<<<ROWS, 256, 0, stream>>>(Yr, QKVG, gnw + l * HH, gnb + l * HH, Eb);
        dim3 g1(ROWS / 128, HH / 128, 1);
        k_mm<3, 0><<<g1, 256, 0, stream>>>(Eb, Bo, Y2, nullptr, curX, ROWS, HH, HH, 0, 0, 0, nullptr);
        k_ln<<<ROWS / 4, 256, 0, stream>>>(Y2, l2w + l * HH, l2b + l * HH, Xn);
        dim3 g2(ROWS / 128, FFND / 128, 1);
        k_mm<1, 1><<<g2, 256, 0, stream>>>(Xn, B1, Hb, fb1 + (size_t)l * FFND, nullptr, ROWS, FFND, HH, 0, 0, 0, nullptr);
        if (l == NLAYERS - 1) {
            k_mm<4, 0><<<g1, 256, 0, stream>>>(Hb, B2, outX, fb2 + (size_t)l * HH, Y2, ROWS, HH, FFND, 0, 0, 0, Xb);
        } else {
            k_mm<2, 0><<<g1, 256, 0, stream>>>(Hb, B2, Xbuf, fb2 + (size_t)l * HH, Y2, ROWS, HH, FFND, 0, 0, 0, nullptr);
        }
        curX = Xbuf;
    }
    dim3 g3(SS / 128, SS / 128, BB);
    k_mm<0, 0><<<g3, 256, 0, stream>>>(Xb, Xb, outG, nullptr, nullptr, SS, SS, HH,
                                       (size_t)SS * HH, (size_t)SS * HH, (size_t)SS * SS, nullptr);
}